// Round 1
// baseline (527.254 us; speedup 1.0000x reference)
//
#include <hip/hip_runtime.h>

#define BB 4
#define NN 512
#define FF 64

__device__ __forceinline__ float silu_f(float v) {
  return v / (1.0f + __expf(-v));
}

__device__ __forceinline__ void fma16(float acc[4][4], const float4 w, const float4 a) {
  acc[0][0] = fmaf(w.x, a.x, acc[0][0]); acc[0][1] = fmaf(w.x, a.y, acc[0][1]);
  acc[0][2] = fmaf(w.x, a.z, acc[0][2]); acc[0][3] = fmaf(w.x, a.w, acc[0][3]);
  acc[1][0] = fmaf(w.y, a.x, acc[1][0]); acc[1][1] = fmaf(w.y, a.y, acc[1][1]);
  acc[1][2] = fmaf(w.y, a.z, acc[1][2]); acc[1][3] = fmaf(w.y, a.w, acc[1][3]);
  acc[2][0] = fmaf(w.z, a.x, acc[2][0]); acc[2][1] = fmaf(w.z, a.y, acc[2][1]);
  acc[2][2] = fmaf(w.z, a.z, acc[2][2]); acc[2][3] = fmaf(w.z, a.w, acc[2][3]);
  acc[3][0] = fmaf(w.w, a.x, acc[3][0]); acc[3][1] = fmaf(w.w, a.y, acc[3][1]);
  acc[3][2] = fmaf(w.w, a.z, acc[3][2]); acc[3][3] = fmaf(w.w, a.w, acc[3][3]);
}

// One workgroup per (b, i). 256 threads.
// Main j-loop: tiles of 64 neighbors, 4 GEMM stages through one LDS buffer.
__global__ __launch_bounds__(256, 2)
void sake_fused(const float* __restrict__ h, const float* __restrict__ x,
                const float* __restrict__ mask,
                const float* __restrict__ We1, const float* __restrict__ be1,
                const float* __restrict__ We2, const float* __restrict__ be2,
                const float* __restrict__ Wc1, const float* __restrict__ bc1,
                const float* __restrict__ Wc2, const float* __restrict__ bc2,
                const float* __restrict__ Wp1, const float* __restrict__ bp1,
                const float* __restrict__ Wp2, const float* __restrict__ bp2,
                const float* __restrict__ Wn1, const float* __restrict__ bn1,
                const float* __restrict__ Wn2, const float* __restrict__ bn2,
                float* __restrict__ out)
{
  __shared__ float sWe1A[64][64];   // We1 rows 0..63 (h_j part), [k][o]
  __shared__ float sWe2[64][64];    // [k][o]
  __shared__ float sBuf[64][68];    // activation buffer [feature][j], padded for b128 align
  __shared__ float sWe1n[64], sBase1[64], sBe2[64], sBc1[64], sBc2[32];
  __shared__ float sNorm2[64], sMask[64], sVec[64][4], sHi[64], sXi[4];
  __shared__ float sHe[64], sCombS[96], sCN[32], sTmp[64], sHcomb[64];

  const int tid = (int)threadIdx.x;
  const int blk = (int)blockIdx.x;
  const int b = blk >> 9;   // blk / 512
  const int i = blk & 511;

  // ---- stage weights / per-row constants ----
  for (int idx = tid; idx < 4096; idx += 256) {
    sWe1A[idx >> 6][idx & 63] = We1[idx];
    sWe2[idx >> 6][idx & 63]  = We2[idx];
  }
  if (tid < 64) {
    sWe1n[tid] = We1[128 * 64 + tid];   // norm2 row of We1
    sBe2[tid]  = be2[tid];
    sBc1[tid]  = bc1[tid];
    sHi[tid]   = h[(b * NN + i) * FF + tid];
  }
  if (tid < 32) sBc2[tid] = bc2[tid];
  if (tid < 3)  sXi[tid] = x[(b * NN + i) * 3 + tid];
  __syncthreads();

  // base1[o] = be1[o] + sum_k h_i[k] * We1[64+k][o]   (the h_i half of layer 1)
  if (tid < 64) {
    float s = be1[tid];
    #pragma unroll 16
    for (int k = 0; k < 64; ++k) s = fmaf(sHi[k], We1[(64 + k) * 64 + tid], s);
    sBase1[tid] = s;
  }
  // consumed after the next __syncthreads inside the tile loop

  // thread tiling for the 64-wide stages: 16 o-groups x 16 j-groups, 4x4 each
  const int og = tid & 15, jg = tid >> 4;
  const int o0 = og * 4, j0 = jg * 4;
  // thread tiling for the C=32 stage: 8 c-groups x 32 j-groups, 4x2 each
  const int cg = tid & 7, jg2 = tid >> 3;
  const int c0 = cg * 4, j0c = jg2 * 2;

  float accHe[4]    = {0.f, 0.f, 0.f, 0.f};
  float accComb[12] = {0.f, 0.f, 0.f, 0.f, 0.f, 0.f, 0.f, 0.f, 0.f, 0.f, 0.f, 0.f};

  for (int jt = 0; jt < 8; ++jt) {
    const int jbase = jt * 64;
    __syncthreads();   // previous tile's reads of sBuf are done

    // ---- stage h_j tile transposed: sBuf[k][j] ----
    {
      const int kk = (tid & 15) * 4;
      const int jr = tid >> 4;
      #pragma unroll
      for (int r = 0; r < 4; ++r) {
        const int j = jr + 16 * r;
        const float4 v = *(const float4*)&h[((size_t)(b * NN + jbase + j)) * FF + kk];
        sBuf[kk + 0][j] = v.x;
        sBuf[kk + 1][j] = v.y;
        sBuf[kk + 2][j] = v.z;
        sBuf[kk + 3][j] = v.w;
      }
    }
    // geometry for this tile
    if (tid < 64) {
      const int j = tid;
      const float dx = x[(b * NN + jbase + j) * 3 + 0] - sXi[0];
      const float dy = x[(b * NN + jbase + j) * 3 + 1] - sXi[1];
      const float dz = x[(b * NN + jbase + j) * 3 + 2] - sXi[2];
      const float n2 = dx * dx + dy * dy + dz * dz;
      const float inv = 1.0f / (n2 * n2 + 1e-10f);   // vec = dx / (norm2^2 + EPS)
      sNorm2[j] = n2;
      sVec[j][0] = dx * inv; sVec[j][1] = dy * inv; sVec[j][2] = dz * inv;
      sMask[j] = mask[((size_t)(b * NN + i)) * NN + jbase + j];
    }
    __syncthreads();

    float acc[4][4];

    // ---------- L1: silu(base1 + h_j @ We1A + norm2 * We1n) ----------
    #pragma unroll
    for (int oi = 0; oi < 4; ++oi) {
      const float bse = sBase1[o0 + oi], wn = sWe1n[o0 + oi];
      #pragma unroll
      for (int ji = 0; ji < 4; ++ji) acc[oi][ji] = fmaf(wn, sNorm2[j0 + ji], bse);
    }
    #pragma unroll 8
    for (int k = 0; k < 64; ++k) {
      const float4 a = *(const float4*)&sBuf[k][j0];
      const float4 w = *(const float4*)&sWe1A[k][o0];
      fma16(acc, w, a);
    }
    #pragma unroll
    for (int oi = 0; oi < 4; ++oi)
      #pragma unroll
      for (int ji = 0; ji < 4; ++ji) acc[oi][ji] = silu_f(acc[oi][ji]);
    __syncthreads();
    #pragma unroll
    for (int oi = 0; oi < 4; ++oi)
      *(float4*)&sBuf[o0 + oi][j0] = make_float4(acc[oi][0], acc[oi][1], acc[oi][2], acc[oi][3]);
    __syncthreads();

    // ---------- L2: h_e_mtx = silu(l1 @ We2 + be2) ----------
    #pragma unroll
    for (int oi = 0; oi < 4; ++oi) {
      const float bse = sBe2[o0 + oi];
      #pragma unroll
      for (int ji = 0; ji < 4; ++ji) acc[oi][ji] = bse;
    }
    #pragma unroll 8
    for (int k = 0; k < 64; ++k) {
      const float4 a = *(const float4*)&sBuf[k][j0];
      const float4 w = *(const float4*)&sWe2[k][o0];
      fma16(acc, w, a);
    }
    #pragma unroll
    for (int oi = 0; oi < 4; ++oi)
      #pragma unroll
      for (int ji = 0; ji < 4; ++ji) acc[oi][ji] = silu_f(acc[oi][ji]);
    // masked aggregation h_e (register partials, reduced at the end)
    #pragma unroll
    for (int oi = 0; oi < 4; ++oi) {
      float s = 0.f;
      #pragma unroll
      for (int ji = 0; ji < 4; ++ji) s = fmaf(acc[oi][ji], sMask[j0 + ji], s);
      accHe[oi] += s;
    }
    __syncthreads();
    #pragma unroll
    for (int oi = 0; oi < 4; ++oi)
      *(float4*)&sBuf[o0 + oi][j0] = make_float4(acc[oi][0], acc[oi][1], acc[oi][2], acc[oi][3]);
    __syncthreads();

    // ---------- C1: silu(h_e_mtx @ Wc1 + bc1)  (Wc1 from L2 cache) ----------
    #pragma unroll
    for (int oi = 0; oi < 4; ++oi) {
      const float bse = sBc1[o0 + oi];
      #pragma unroll
      for (int ji = 0; ji < 4; ++ji) acc[oi][ji] = bse;
    }
    #pragma unroll 8
    for (int k = 0; k < 64; ++k) {
      const float4 a = *(const float4*)&sBuf[k][j0];
      const float4 w = *(const float4*)&Wc1[k * 64 + o0];
      fma16(acc, w, a);
    }
    #pragma unroll
    for (int oi = 0; oi < 4; ++oi)
      #pragma unroll
      for (int ji = 0; ji < 4; ++ji) acc[oi][ji] = silu_f(acc[oi][ji]);
    __syncthreads();
    #pragma unroll
    for (int oi = 0; oi < 4; ++oi)
      *(float4*)&sBuf[o0 + oi][j0] = make_float4(acc[oi][0], acc[oi][1], acc[oi][2], acc[oi][3]);
    __syncthreads();

    // ---------- C2: coeff = c1 @ Wc2 + bc2 (no silu); accumulate comb ----------
    {
      float acc2[4][2];
      #pragma unroll
      for (int ci = 0; ci < 4; ++ci) {
        const float bse = sBc2[c0 + ci];
        acc2[ci][0] = bse; acc2[ci][1] = bse;
      }
      #pragma unroll 8
      for (int k = 0; k < 64; ++k) {
        const float2 a = *(const float2*)&sBuf[k][j0c];
        const float4 w = *(const float4*)&Wc2[k * 32 + c0];
        acc2[0][0] = fmaf(w.x, a.x, acc2[0][0]); acc2[0][1] = fmaf(w.x, a.y, acc2[0][1]);
        acc2[1][0] = fmaf(w.y, a.x, acc2[1][0]); acc2[1][1] = fmaf(w.y, a.y, acc2[1][1]);
        acc2[2][0] = fmaf(w.z, a.x, acc2[2][0]); acc2[2][1] = fmaf(w.z, a.y, acc2[2][1]);
        acc2[3][0] = fmaf(w.w, a.x, acc2[3][0]); acc2[3][1] = fmaf(w.w, a.y, acc2[3][1]);
      }
      #pragma unroll
      for (int ji = 0; ji < 2; ++ji) {
        const int jl = j0c + ji;
        const float m  = sMask[jl];
        const float v0 = sVec[jl][0] * m, v1 = sVec[jl][1] * m, v2 = sVec[jl][2] * m;
        #pragma unroll
        for (int ci = 0; ci < 4; ++ci) {
          accComb[ci * 3 + 0] = fmaf(acc2[ci][ji], v0, accComb[ci * 3 + 0]);
          accComb[ci * 3 + 1] = fmaf(acc2[ci][ji], v1, accComb[ci * 3 + 1]);
          accComb[ci * 3 + 2] = fmaf(acc2[ci][ji], v2, accComb[ci * 3 + 2]);
        }
      }
    }
    // next loop-top __syncthreads protects sBuf
  }

  // -------- reductions + epilogue --------
  float* red = &sBuf[0][0];   // 4352 floats of scratch
  __syncthreads();

  // h_e: reduce 16 jg partials per o
  #pragma unroll
  for (int oi = 0; oi < 4; ++oi) red[jg * 64 + o0 + oi] = accHe[oi];
  __syncthreads();
  if (tid < 64) {
    float s = 0.f;
    #pragma unroll
    for (int g = 0; g < 16; ++g) s += red[g * 64 + tid];
    sHe[tid] = s;
  }
  __syncthreads();

  // comb_sum: reduce 32 jg2 partials per (c,d)
  #pragma unroll
  for (int ci = 0; ci < 4; ++ci)
    #pragma unroll
    for (int d = 0; d < 3; ++d) red[jg2 * 96 + (c0 + ci) * 3 + d] = accComb[ci * 3 + d];
  __syncthreads();
  if (tid < 96) {
    float s = 0.f;
    #pragma unroll
    for (int g = 0; g < 32; ++g) s += red[g * 96 + tid];
    sCombS[tid] = s;
  }
  __syncthreads();
  if (tid < 32) {
    const float s0 = sCombS[tid * 3 + 0], s1 = sCombS[tid * 3 + 1], s2 = sCombS[tid * 3 + 2];
    sCN[tid] = s0 * s0 + s1 * s1 + s2 * s2;   // comb_norm
  }
  __syncthreads();

  // h_comb = silu(comb_norm @ Wp1 + bp1) @ Wp2 + bp2
  if (tid < 64) {
    float s = bp1[tid];
    #pragma unroll 8
    for (int c = 0; c < 32; ++c) s = fmaf(sCN[c], Wp1[c * 64 + tid], s);
    sTmp[tid] = silu_f(s);
  }
  __syncthreads();
  if (tid < 64) {
    float s = bp2[tid];
    #pragma unroll 16
    for (int k = 0; k < 64; ++k) s = fmaf(sTmp[k], Wp2[k * 64 + tid], s);
    sHcomb[tid] = s;
  }
  __syncthreads();

  // node MLP: out = silu([h, h_e, h_comb] @ Wn1 + bn1) @ Wn2 + bn2 ; h_new = h + out
  if (tid < 64) {
    float s = bn1[tid];
    #pragma unroll 16
    for (int m = 0; m < 64; ++m) s = fmaf(sHi[m],    Wn1[m * 64 + tid],         s);
    #pragma unroll 16
    for (int m = 0; m < 64; ++m) s = fmaf(sHe[m],    Wn1[(64 + m) * 64 + tid],  s);
    #pragma unroll 16
    for (int m = 0; m < 64; ++m) s = fmaf(sHcomb[m], Wn1[(128 + m) * 64 + tid], s);
    sTmp[tid] = silu_f(s);
  }
  __syncthreads();
  if (tid < 64) {
    float s = bn2[tid];
    #pragma unroll 16
    for (int k = 0; k < 64; ++k) s = fmaf(sTmp[k], Wn2[k * 64 + tid], s);
    out[(b * NN + i) * FF + tid] = sHi[tid] + s;
  } else if (tid < 67) {
    const int d = tid - 64;
    out[BB * NN * FF + (b * NN + i) * 3 + d] = x[(b * NN + i) * 3 + d];
  }
}

extern "C" void kernel_launch(void* const* d_in, const int* in_sizes, int n_in,
                              void* d_out, int out_size, void* d_ws, size_t ws_size,
                              hipStream_t stream) {
  const float* h    = (const float*)d_in[0];
  const float* x    = (const float*)d_in[1];
  const float* mask = (const float*)d_in[2];
  const float* We1  = (const float*)d_in[3];
  const float* be1  = (const float*)d_in[4];
  const float* We2  = (const float*)d_in[5];
  const float* be2  = (const float*)d_in[6];
  const float* Wc1  = (const float*)d_in[7];
  const float* bc1  = (const float*)d_in[8];
  const float* Wc2  = (const float*)d_in[9];
  const float* bc2  = (const float*)d_in[10];
  const float* Wp1  = (const float*)d_in[11];
  const float* bp1  = (const float*)d_in[12];
  const float* Wp2  = (const float*)d_in[13];
  const float* bp2  = (const float*)d_in[14];
  const float* Wn1  = (const float*)d_in[15];
  const float* bn1  = (const float*)d_in[16];
  const float* Wn2  = (const float*)d_in[17];
  const float* bn2  = (const float*)d_in[18];
  float* out = (float*)d_out;

  dim3 grid(BB * NN), block(256);
  hipLaunchKernelGGL(sake_fused, grid, block, 0, stream,
                     h, x, mask, We1, be1, We2, be2, Wc1, bc1, Wc2, bc2,
                     Wp1, bp1, Wp2, bp2, Wn1, bn1, Wn2, bn2, out);
}

// Round 2
// 219.283 us; speedup vs baseline: 2.4044x; 2.4044x over previous
//
#include <hip/hip_runtime.h>

#define BB 4
#define NN 512
#define FF 64

typedef __attribute__((ext_vector_type(8))) short short8v;   // 8 bf16 = 4 VGPR
typedef __attribute__((ext_vector_type(4))) float f32x4;

__device__ __forceinline__ float silu_f(float v) {
  return v / (1.0f + __expf(-v));
}
__device__ __forceinline__ unsigned short f2bf(float f) {
  unsigned int u = __float_as_uint(f);
  unsigned int r = (u + 0x7FFFu + ((u >> 16) & 1u)) >> 16;   // RNE
  return (unsigned short)r;
}
__device__ __forceinline__ float bf2f(unsigned short s) {
  return __uint_as_float(((unsigned int)s) << 16);
}

// act LDS addressing: [j][k] bf16 rows of 128B, 16B slots XOR-swizzled by j.
#define AIDX(j, k) ((((j) << 6)) | (((((k) >> 3) ^ ((j) & 7))) << 3) | ((k) & 7))

// ---------------- prep kernel ----------------
// wg 0..63: G[b,j,o] = h_j @ We1[0:64];  Base[b,i,o] = be1 + h_i @ We1[64:128]
// wg 64   : split-transpose weights -> Wt{2,3,4}{hi,lo}[out][in] bf16
__global__ void sake_prep(const float* __restrict__ h, const float* __restrict__ We1,
                          const float* __restrict__ be1, const float* __restrict__ We2,
                          const float* __restrict__ Wc1, const float* __restrict__ Wc2,
                          float* __restrict__ G, float* __restrict__ Base,
                          unsigned short* __restrict__ w2h, unsigned short* __restrict__ w2l,
                          unsigned short* __restrict__ w3h, unsigned short* __restrict__ w3l,
                          unsigned short* __restrict__ w4h, unsigned short* __restrict__ w4l)
{
  const int wg = (int)blockIdx.x, tid = (int)threadIdx.x;
  if (wg < 64) {
    __shared__ float sH[32][64];
    const int r0 = wg * 32;
    for (int idx = tid; idx < 2048; idx += 256) sH[idx >> 6][idx & 63] = h[r0 * 64 + idx];
    __syncthreads();
    const int rl = tid >> 3;          // row 0..31
    const int o0 = (tid & 7) * 8;     // 8 outputs
    float aG[8], aB[8];
    #pragma unroll
    for (int o = 0; o < 8; ++o) { aG[o] = 0.f; aB[o] = be1[o0 + o]; }
    for (int k = 0; k < 64; ++k) {
      const float hv = sH[rl][k];
      const float4 g0 = *(const float4*)&We1[k * 64 + o0];
      const float4 g1 = *(const float4*)&We1[k * 64 + o0 + 4];
      const float4 b0 = *(const float4*)&We1[(64 + k) * 64 + o0];
      const float4 b1 = *(const float4*)&We1[(64 + k) * 64 + o0 + 4];
      aG[0] = fmaf(hv, g0.x, aG[0]); aG[1] = fmaf(hv, g0.y, aG[1]);
      aG[2] = fmaf(hv, g0.z, aG[2]); aG[3] = fmaf(hv, g0.w, aG[3]);
      aG[4] = fmaf(hv, g1.x, aG[4]); aG[5] = fmaf(hv, g1.y, aG[5]);
      aG[6] = fmaf(hv, g1.z, aG[6]); aG[7] = fmaf(hv, g1.w, aG[7]);
      aB[0] = fmaf(hv, b0.x, aB[0]); aB[1] = fmaf(hv, b0.y, aB[1]);
      aB[2] = fmaf(hv, b0.z, aB[2]); aB[3] = fmaf(hv, b0.w, aB[3]);
      aB[4] = fmaf(hv, b1.x, aB[4]); aB[5] = fmaf(hv, b1.y, aB[5]);
      aB[6] = fmaf(hv, b1.z, aB[6]); aB[7] = fmaf(hv, b1.w, aB[7]);
    }
    const size_t base = (size_t)(r0 + rl) * 64 + o0;
    *(float4*)&G[base]        = make_float4(aG[0], aG[1], aG[2], aG[3]);
    *(float4*)&G[base + 4]    = make_float4(aG[4], aG[5], aG[6], aG[7]);
    *(float4*)&Base[base]     = make_float4(aB[0], aB[1], aB[2], aB[3]);
    *(float4*)&Base[base + 4] = make_float4(aB[4], aB[5], aB[6], aB[7]);
  } else {
    for (int idx = tid; idx < 10240; idx += 256) {
      float w; unsigned short *ph, *pl; int pos;
      if (idx < 4096)      { const int o = idx >> 6,          k = idx & 63;
                             w = We2[k * 64 + o]; ph = w2h; pl = w2l; pos = o * 64 + k; }
      else if (idx < 8192) { const int t = idx - 4096, o = t >> 6, k = t & 63;
                             w = Wc1[k * 64 + o]; ph = w3h; pl = w3l; pos = o * 64 + k; }
      else                 { const int t = idx - 8192, c = t >> 6, k = t & 63;
                             w = Wc2[k * 32 + c]; ph = w4h; pl = w4l; pos = c * 64 + k; }
      const unsigned short hi = f2bf(w);
      const unsigned short lo = f2bf(w - bf2f(hi));
      ph[pos] = hi; pl[pos] = lo;
    }
  }
}

// ---------------- main kernel ----------------
// One wg per (b,i), 256 thr = 4 waves. j in tiles of 64.
// All pairwise GEMMs: D[out_feat][j] = Wt(A-frags, regs) x act(B-frags, LDS).
__global__ __launch_bounds__(256, 2)
void sake_mfma(const float* __restrict__ h, const float* __restrict__ x,
               const float* __restrict__ mask,
               const float* __restrict__ We1, const float* __restrict__ be2,
               const float* __restrict__ bc1, const float* __restrict__ bc2,
               const float* __restrict__ Wp1, const float* __restrict__ bp1,
               const float* __restrict__ Wp2, const float* __restrict__ bp2,
               const float* __restrict__ Wn1, const float* __restrict__ bn1,
               const float* __restrict__ Wn2, const float* __restrict__ bn2,
               const float* __restrict__ G, const float* __restrict__ Base,
               const unsigned short* __restrict__ w2h, const unsigned short* __restrict__ w2l,
               const unsigned short* __restrict__ w3h, const unsigned short* __restrict__ w3l,
               const unsigned short* __restrict__ w4h, const unsigned short* __restrict__ w4l,
               float* __restrict__ out)
{
  __shared__ unsigned short sAh[2 * 4096];   // act hi, ping/pong [j][k] swizzled
  __shared__ unsigned short sAl[2 * 4096];   // act lo
  __shared__ float sVecM[64][4];             // vec*mask per j
  __shared__ float sMask[64];
  __shared__ float sBase[64], sW1n[64], sHi[64], sXi[4];
  __shared__ float sHe[64], sCombP[4 * 48], sCN[32], sTmp[64], sHcomb[64];

  const int tid  = (int)threadIdx.x;
  const int blk  = (int)blockIdx.x;
  const int b    = blk >> 9;
  const int i    = blk & 511;
  const int lane = tid & 63;
  const int wid  = tid >> 6;
  const int l15  = lane & 15;
  const int lg   = lane >> 4;            // 0..3
  const int mb   = wid * 16;             // feat block (L2/C1)
  const int mb2  = (wid >> 1) * 16;      // coeff block (C2)

  // per-wg constants
  if (tid < 64) {
    sBase[tid] = Base[((size_t)(b * NN + i)) * 64 + tid];
    sW1n[tid]  = We1[128 * 64 + tid];
    sHi[tid]   = h[((size_t)(b * NN + i)) * 64 + tid];
  }
  if (tid < 3) sXi[tid] = x[((size_t)(b * NN + i)) * 3 + tid];

  // preload weight A-frags: lane m = blk+l15, k = ks*32 + lg*8 .. +7
  short8v w2hF[2], w2lF[2], w3hF[2], w3lF[2], w4hF[2], w4lF[2];
  #pragma unroll
  for (int ks = 0; ks < 2; ++ks) {
    const int ko = ks * 32 + lg * 8;
    w2hF[ks] = *(const short8v*)&w2h[(mb  + l15) * 64 + ko];
    w2lF[ks] = *(const short8v*)&w2l[(mb  + l15) * 64 + ko];
    w3hF[ks] = *(const short8v*)&w3h[(mb  + l15) * 64 + ko];
    w3lF[ks] = *(const short8v*)&w3l[(mb  + l15) * 64 + ko];
    w4hF[ks] = *(const short8v*)&w4h[(mb2 + l15) * 64 + ko];
    w4lF[ks] = *(const short8v*)&w4l[(mb2 + l15) * 64 + ko];
  }
  float be2v[4], bc1v[4], bc2v[4];
  #pragma unroll
  for (int r = 0; r < 4; ++r) {
    be2v[r] = be2[mb  + lg * 4 + r];
    bc1v[r] = bc1[mb  + lg * 4 + r];
    bc2v[r] = bc2[mb2 + lg * 4 + r];
  }

  float heAcc[4] = {0.f, 0.f, 0.f, 0.f};
  float cAcc[4][3] = {};

  for (int jt = 0; jt < 8; ++jt) {
    const int jb = jt * 64;
    __syncthreads();   // A: prev tile's C2 reads + sVecM reads done

    if (tid < 64) {    // geometry for this tile
      const int j = tid;
      const size_t xo = ((size_t)(b * NN + jb + j)) * 3;
      const float dx = x[xo + 0] - sXi[0];
      const float dy = x[xo + 1] - sXi[1];
      const float dz = x[xo + 2] - sXi[2];
      const float n2 = dx * dx + dy * dy + dz * dz;
      const float inv = 1.0f / (n2 * n2 + 1e-10f);
      const float m = mask[((size_t)(b * NN + i)) * NN + jb + j];
      sVecM[j][0] = dx * inv * m; sVecM[j][1] = dy * inv * m; sVecM[j][2] = dz * inv * m;
      sMask[j] = m;
    }

    // ---- L1 elementwise: act1 = silu(G + Base + n2*We1n) -> buf0 ----
    {
      const int j = l15 + wid * 16;          // tile-local j (4 threads per j)
      const int jglob = jb + j;
      const size_t xo = ((size_t)(b * NN + jglob)) * 3;
      const float dx = x[xo + 0] - sXi[0];
      const float dy = x[xo + 1] - sXi[1];
      const float dz = x[xo + 2] - sXi[2];
      const float n2 = dx * dx + dy * dy + dz * dz;
      #pragma unroll
      for (int kk = 0; kk < 4; ++kk) {
        const int kb = lg * 16 + kk * 4;
        const float4 g4 = *(const float4*)&G[((size_t)(b * NN + jglob)) * 64 + kb];
        const float4 bs = *(const float4*)&sBase[kb];
        const float4 wn = *(const float4*)&sW1n[kb];
        const float v0 = silu_f(g4.x + bs.x + n2 * wn.x);
        const float v1 = silu_f(g4.y + bs.y + n2 * wn.y);
        const float v2 = silu_f(g4.z + bs.z + n2 * wn.z);
        const float v3 = silu_f(g4.w + bs.w + n2 * wn.w);
        const unsigned short h0 = f2bf(v0), h1 = f2bf(v1), h2 = f2bf(v2), h3 = f2bf(v3);
        const unsigned short l0 = f2bf(v0 - bf2f(h0)), l1 = f2bf(v1 - bf2f(h1));
        const unsigned short l2 = f2bf(v2 - bf2f(h2)), l3 = f2bf(v3 - bf2f(h3));
        const int a = AIDX(j, kb);
        *(uint2*)&sAh[a] = make_uint2((unsigned)h0 | ((unsigned)h1 << 16),
                                      (unsigned)h2 | ((unsigned)h3 << 16));
        *(uint2*)&sAl[a] = make_uint2((unsigned)l0 | ((unsigned)l1 << 16),
                                      (unsigned)l2 | ((unsigned)l3 << 16));
      }
    }
    __syncthreads();   // B: buf0 + geometry ready

    // ---- L2: act2 = silu(act1 @ We2 + be2) -> buf1 ; h_e accum ----
    #pragma unroll
    for (int nf = 0; nf < 4; ++nf) {
      const int jn = nf * 16 + l15;
      f32x4 acc = { be2v[0], be2v[1], be2v[2], be2v[3] };
      #pragma unroll
      for (int ks = 0; ks < 2; ++ks) {
        const int kb = ks * 32 + lg * 8;
        const short8v bh = *(const short8v*)&sAh[AIDX(jn, kb)];
        const short8v bl = *(const short8v*)&sAl[AIDX(jn, kb)];
        acc = __builtin_amdgcn_mfma_f32_16x16x32_bf16(w2hF[ks], bh, acc, 0, 0, 0);
        acc = __builtin_amdgcn_mfma_f32_16x16x32_bf16(w2hF[ks], bl, acc, 0, 0, 0);
        acc = __builtin_amdgcn_mfma_f32_16x16x32_bf16(w2lF[ks], bh, acc, 0, 0, 0);
      }
      const float m = sMask[jn];
      float v[4];
      #pragma unroll
      for (int r = 0; r < 4; ++r) { v[r] = silu_f(acc[r]); heAcc[r] = fmaf(v[r], m, heAcc[r]); }
      const unsigned short h0 = f2bf(v[0]), h1 = f2bf(v[1]), h2 = f2bf(v[2]), h3 = f2bf(v[3]);
      const unsigned short l0 = f2bf(v[0] - bf2f(h0)), l1 = f2bf(v[1] - bf2f(h1));
      const unsigned short l2 = f2bf(v[2] - bf2f(h2)), l3 = f2bf(v[3] - bf2f(h3));
      const int a = 4096 + AIDX(jn, mb + lg * 4);
      *(uint2*)&sAh[a] = make_uint2((unsigned)h0 | ((unsigned)h1 << 16),
                                    (unsigned)h2 | ((unsigned)h3 << 16));
      *(uint2*)&sAl[a] = make_uint2((unsigned)l0 | ((unsigned)l1 << 16),
                                    (unsigned)l2 | ((unsigned)l3 << 16));
    }
    __syncthreads();   // C: buf1 ready (all buf0 reads done)

    // ---- C1: act3 = silu(act2 @ Wc1 + bc1) -> buf0 ----
    #pragma unroll
    for (int nf = 0; nf < 4; ++nf) {
      const int jn = nf * 16 + l15;
      f32x4 acc = { bc1v[0], bc1v[1], bc1v[2], bc1v[3] };
      #pragma unroll
      for (int ks = 0; ks < 2; ++ks) {
        const int kb = ks * 32 + lg * 8;
        const short8v bh = *(const short8v*)&sAh[4096 + AIDX(jn, kb)];
        const short8v bl = *(const short8v*)&sAl[4096 + AIDX(jn, kb)];
        acc = __builtin_amdgcn_mfma_f32_16x16x32_bf16(w3hF[ks], bh, acc, 0, 0, 0);
        acc = __builtin_amdgcn_mfma_f32_16x16x32_bf16(w3hF[ks], bl, acc, 0, 0, 0);
        acc = __builtin_amdgcn_mfma_f32_16x16x32_bf16(w3lF[ks], bh, acc, 0, 0, 0);
      }
      float v[4];
      #pragma unroll
      for (int r = 0; r < 4; ++r) v[r] = silu_f(acc[r]);
      const unsigned short h0 = f2bf(v[0]), h1 = f2bf(v[1]), h2 = f2bf(v[2]), h3 = f2bf(v[3]);
      const unsigned short l0 = f2bf(v[0] - bf2f(h0)), l1 = f2bf(v[1] - bf2f(h1));
      const unsigned short l2 = f2bf(v[2] - bf2f(h2)), l3 = f2bf(v[3] - bf2f(h3));
      const int a = AIDX(jn, mb + lg * 4);
      *(uint2*)&sAh[a] = make_uint2((unsigned)h0 | ((unsigned)h1 << 16),
                                    (unsigned)h2 | ((unsigned)h3 << 16));
      *(uint2*)&sAl[a] = make_uint2((unsigned)l0 | ((unsigned)l1 << 16),
                                    (unsigned)l2 | ((unsigned)l3 << 16));
    }
    __syncthreads();   // D: buf0(act3) ready

    // ---- C2: coeff = act3 @ Wc2 + bc2 ; comb accumulation ----
    #pragma unroll
    for (int nf = 0; nf < 2; ++nf) {
      const int jn = (wid & 1) * 32 + nf * 16 + l15;
      f32x4 acc = { bc2v[0], bc2v[1], bc2v[2], bc2v[3] };
      #pragma unroll
      for (int ks = 0; ks < 2; ++ks) {
        const int kb = ks * 32 + lg * 8;
        const short8v bh = *(const short8v*)&sAh[AIDX(jn, kb)];
        const short8v bl = *(const short8v*)&sAl[AIDX(jn, kb)];
        acc = __builtin_amdgcn_mfma_f32_16x16x32_bf16(w4hF[ks], bh, acc, 0, 0, 0);
        acc = __builtin_amdgcn_mfma_f32_16x16x32_bf16(w4hF[ks], bl, acc, 0, 0, 0);
        acc = __builtin_amdgcn_mfma_f32_16x16x32_bf16(w4lF[ks], bh, acc, 0, 0, 0);
      }
      const float vm0 = sVecM[jn][0], vm1 = sVecM[jn][1], vm2 = sVecM[jn][2];
      #pragma unroll
      for (int r = 0; r < 4; ++r) {
        cAcc[r][0] = fmaf(acc[r], vm0, cAcc[r][0]);
        cAcc[r][1] = fmaf(acc[r], vm1, cAcc[r][1]);
        cAcc[r][2] = fmaf(acc[r], vm2, cAcc[r][2]);
      }
    }
  }

  // -------- reductions --------
  #pragma unroll
  for (int r = 0; r < 4; ++r) {
    float s = heAcc[r];
    s += __shfl_xor(s, 1); s += __shfl_xor(s, 2); s += __shfl_xor(s, 4); s += __shfl_xor(s, 8);
    if (l15 == 0) sHe[mb + lg * 4 + r] = s;
  }
  #pragma unroll
  for (int r = 0; r < 4; ++r)
    #pragma unroll
    for (int d = 0; d < 3; ++d) {
      float s = cAcc[r][d];
      s += __shfl_xor(s, 1); s += __shfl_xor(s, 2); s += __shfl_xor(s, 4); s += __shfl_xor(s, 8);
      if (l15 == 0) sCombP[wid * 48 + (lg * 4 + r) * 3 + d] = s;
    }
  __syncthreads();
  if (tid < 32) {
    const int c = tid, w0 = (c >> 4) * 2, cl = c & 15;
    const float s0 = sCombP[w0 * 48 + cl * 3 + 0] + sCombP[(w0 + 1) * 48 + cl * 3 + 0];
    const float s1 = sCombP[w0 * 48 + cl * 3 + 1] + sCombP[(w0 + 1) * 48 + cl * 3 + 1];
    const float s2 = sCombP[w0 * 48 + cl * 3 + 2] + sCombP[(w0 + 1) * 48 + cl * 3 + 2];
    sCN[c] = s0 * s0 + s1 * s1 + s2 * s2;
  }
  __syncthreads();

  // -------- epilogue MLPs (fp32, tiny) --------
  if (tid < 64) {
    float s = bp1[tid];
    #pragma unroll 8
    for (int c = 0; c < 32; ++c) s = fmaf(sCN[c], Wp1[c * 64 + tid], s);
    sTmp[tid] = silu_f(s);
  }
  __syncthreads();
  if (tid < 64) {
    float s = bp2[tid];
    #pragma unroll 16
    for (int k = 0; k < 64; ++k) s = fmaf(sTmp[k], Wp2[k * 64 + tid], s);
    sHcomb[tid] = s;
  }
  __syncthreads();
  if (tid < 64) {
    float s = bn1[tid];
    #pragma unroll 16
    for (int m = 0; m < 64; ++m) s = fmaf(sHi[m],    Wn1[m * 64 + tid],         s);
    #pragma unroll 16
    for (int m = 0; m < 64; ++m) s = fmaf(sHe[m],    Wn1[(64 + m) * 64 + tid],  s);
    #pragma unroll 16
    for (int m = 0; m < 64; ++m) s = fmaf(sHcomb[m], Wn1[(128 + m) * 64 + tid], s);
    sTmp[tid] = silu_f(s);
  }
  __syncthreads();
  if (tid < 64) {
    float s = bn2[tid];
    #pragma unroll 16
    for (int k = 0; k < 64; ++k) s = fmaf(sTmp[k], Wn2[k * 64 + tid], s);
    out[((size_t)(b * NN + i)) * 64 + tid] = sHi[tid] + s;
  } else if (tid < 67) {
    const int d = tid - 64;
    out[(size_t)BB * NN * FF + ((size_t)(b * NN + i)) * 3 + d] = x[((size_t)(b * NN + i)) * 3 + d];
  }
}

extern "C" void kernel_launch(void* const* d_in, const int* in_sizes, int n_in,
                              void* d_out, int out_size, void* d_ws, size_t ws_size,
                              hipStream_t stream) {
  const float* h    = (const float*)d_in[0];
  const float* x    = (const float*)d_in[1];
  const float* mask = (const float*)d_in[2];
  const float* We1  = (const float*)d_in[3];
  const float* be1  = (const float*)d_in[4];
  const float* We2  = (const float*)d_in[5];
  const float* be2  = (const float*)d_in[6];
  const float* Wc1  = (const float*)d_in[7];
  const float* bc1  = (const float*)d_in[8];
  const float* Wc2  = (const float*)d_in[9];
  const float* bc2  = (const float*)d_in[10];
  const float* Wp1  = (const float*)d_in[11];
  const float* bp1  = (const float*)d_in[12];
  const float* Wp2  = (const float*)d_in[13];
  const float* bp2  = (const float*)d_in[14];
  const float* Wn1  = (const float*)d_in[15];
  const float* bn1  = (const float*)d_in[16];
  const float* Wn2  = (const float*)d_in[17];
  const float* bn2  = (const float*)d_in[18];
  float* out = (float*)d_out;

  // workspace layout
  float* G    = (float*)d_ws;                       // 2048*64 f32
  float* Base = G + 2048 * 64;                      // 2048*64 f32
  unsigned short* w2h = (unsigned short*)(Base + 2048 * 64);
  unsigned short* w2l = w2h + 4096;
  unsigned short* w3h = w2l + 4096;
  unsigned short* w3l = w3h + 4096;
  unsigned short* w4h = w3l + 4096;
  unsigned short* w4l = w4h + 2048;

  hipLaunchKernelGGL(sake_prep, dim3(65), dim3(256), 0, stream,
                     h, We1, be1, We2, Wc1, Wc2, G, Base,
                     w2h, w2l, w3h, w3l, w4h, w4l);
  hipLaunchKernelGGL(sake_mfma, dim3(BB * NN), dim3(256), 0, stream,
                     h, x, mask, We1, be2, bc1, bc2,
                     Wp1, bp1, Wp2, bp2, Wn1, bn1, Wn2, bn2,
                     G, Base, w2h, w2l, w3h, w3l, w4h, w4l, out);
}

// Round 3
// 161.531 us; speedup vs baseline: 3.2641x; 1.3575x over previous
//
#include <hip/hip_runtime.h>

#define BB 4
#define NN 512
#define FF 64

typedef __attribute__((ext_vector_type(8))) short short8v;   // 8 bf16 = 4 VGPR
typedef __attribute__((ext_vector_type(4))) float f32x4;

__device__ __forceinline__ float silu_f(float v) {
  // raw v_rcp_f32 instead of IEEE divide chain; ~1 ulp, fine at our threshold
  return v * __builtin_amdgcn_rcpf(1.0f + __expf(-v));
}
__device__ __forceinline__ unsigned short f2bf(float f) {
  unsigned int u = __float_as_uint(f);
  unsigned int r = (u + 0x7FFFu + ((u >> 16) & 1u)) >> 16;   // RNE (prep kernel only)
  return (unsigned short)r;
}
__device__ __forceinline__ float bf2f(unsigned short s) {
  return __uint_as_float(((unsigned int)s) << 16);
}
// packed f32x2 -> bf16x2 (RNE), low16 = a
__device__ __forceinline__ unsigned cvt_pk_bf16(float a, float b) {
  unsigned r;
  asm("v_cvt_pk_bf16_f32 %0, %1, %2" : "=v"(r) : "v"(a), "v"(b));
  return r;
}

// act LDS addressing: [j][k] bf16 rows of 128B, 16B slots XOR-swizzled by j.
#define AIDX(j, k) ((((j) << 6)) | (((((k) >> 3) ^ ((j) & 7))) << 3) | ((k) & 7))

// ---------------- prep kernel ----------------
// wg 0..63: G[b,j,o] = h_j @ We1[0:64];  Base[b,i,o] = be1 + h_i @ We1[64:128]
// wg 64   : split-transpose weights -> Wt{2,3,4}{hi,lo}[out][in] bf16
__global__ void sake_prep(const float* __restrict__ h, const float* __restrict__ We1,
                          const float* __restrict__ be1, const float* __restrict__ We2,
                          const float* __restrict__ Wc1, const float* __restrict__ Wc2,
                          float* __restrict__ G, float* __restrict__ Base,
                          unsigned short* __restrict__ w2h, unsigned short* __restrict__ w2l,
                          unsigned short* __restrict__ w3h, unsigned short* __restrict__ w3l,
                          unsigned short* __restrict__ w4h, unsigned short* __restrict__ w4l)
{
  const int wg = (int)blockIdx.x, tid = (int)threadIdx.x;
  if (wg < 64) {
    __shared__ float sH[32][64];
    const int r0 = wg * 32;
    for (int idx = tid; idx < 2048; idx += 256) sH[idx >> 6][idx & 63] = h[r0 * 64 + idx];
    __syncthreads();
    const int rl = tid >> 3;          // row 0..31
    const int o0 = (tid & 7) * 8;     // 8 outputs
    float aG[8], aB[8];
    #pragma unroll
    for (int o = 0; o < 8; ++o) { aG[o] = 0.f; aB[o] = be1[o0 + o]; }
    for (int k = 0; k < 64; ++k) {
      const float hv = sH[rl][k];
      const float4 g0 = *(const float4*)&We1[k * 64 + o0];
      const float4 g1 = *(const float4*)&We1[k * 64 + o0 + 4];
      const float4 b0 = *(const float4*)&We1[(64 + k) * 64 + o0];
      const float4 b1 = *(const float4*)&We1[(64 + k) * 64 + o0 + 4];
      aG[0] = fmaf(hv, g0.x, aG[0]); aG[1] = fmaf(hv, g0.y, aG[1]);
      aG[2] = fmaf(hv, g0.z, aG[2]); aG[3] = fmaf(hv, g0.w, aG[3]);
      aG[4] = fmaf(hv, g1.x, aG[4]); aG[5] = fmaf(hv, g1.y, aG[5]);
      aG[6] = fmaf(hv, g1.z, aG[6]); aG[7] = fmaf(hv, g1.w, aG[7]);
      aB[0] = fmaf(hv, b0.x, aB[0]); aB[1] = fmaf(hv, b0.y, aB[1]);
      aB[2] = fmaf(hv, b0.z, aB[2]); aB[3] = fmaf(hv, b0.w, aB[3]);
      aB[4] = fmaf(hv, b1.x, aB[4]); aB[5] = fmaf(hv, b1.y, aB[5]);
      aB[6] = fmaf(hv, b1.z, aB[6]); aB[7] = fmaf(hv, b1.w, aB[7]);
    }
    const size_t base = (size_t)(r0 + rl) * 64 + o0;
    *(float4*)&G[base]        = make_float4(aG[0], aG[1], aG[2], aG[3]);
    *(float4*)&G[base + 4]    = make_float4(aG[4], aG[5], aG[6], aG[7]);
    *(float4*)&Base[base]     = make_float4(aB[0], aB[1], aB[2], aB[3]);
    *(float4*)&Base[base + 4] = make_float4(aB[4], aB[5], aB[6], aB[7]);
  } else {
    for (int idx = tid; idx < 10240; idx += 256) {
      float w; unsigned short *ph, *pl; int pos;
      if (idx < 4096)      { const int o = idx >> 6,          k = idx & 63;
                             w = We2[k * 64 + o]; ph = w2h; pl = w2l; pos = o * 64 + k; }
      else if (idx < 8192) { const int t = idx - 4096, o = t >> 6, k = t & 63;
                             w = Wc1[k * 64 + o]; ph = w3h; pl = w3l; pos = o * 64 + k; }
      else                 { const int t = idx - 8192, c = t >> 6, k = t & 63;
                             w = Wc2[k * 32 + c]; ph = w4h; pl = w4l; pos = c * 64 + k; }
      const unsigned short hi = f2bf(w);
      const unsigned short lo = f2bf(w - bf2f(hi));
      ph[pos] = hi; pl[pos] = lo;
    }
  }
}

// split 4 f32 -> hi/lo packed pairs, store to LDS at element index a
__device__ __forceinline__ void split_store4(unsigned short* sAh, unsigned short* sAl,
                                             int a, float v0, float v1, float v2, float v3) {
  const unsigned uh01 = cvt_pk_bf16(v0, v1);
  const unsigned uh23 = cvt_pk_bf16(v2, v3);
  const float h0f = __uint_as_float(uh01 << 16);
  const float h1f = __uint_as_float(uh01 & 0xFFFF0000u);
  const float h2f = __uint_as_float(uh23 << 16);
  const float h3f = __uint_as_float(uh23 & 0xFFFF0000u);
  const unsigned ul01 = cvt_pk_bf16(v0 - h0f, v1 - h1f);
  const unsigned ul23 = cvt_pk_bf16(v2 - h2f, v3 - h3f);
  *(uint2*)&sAh[a] = make_uint2(uh01, uh23);
  *(uint2*)&sAl[a] = make_uint2(ul01, ul23);
}

// ---------------- main kernel ----------------
__global__ __launch_bounds__(256, 2)
void sake_mfma(const float* __restrict__ h, const float* __restrict__ x,
               const float* __restrict__ mask,
               const float* __restrict__ We1, const float* __restrict__ be2,
               const float* __restrict__ bc1, const float* __restrict__ bc2,
               const float* __restrict__ Wp1, const float* __restrict__ bp1,
               const float* __restrict__ Wp2, const float* __restrict__ bp2,
               const float* __restrict__ Wn1, const float* __restrict__ bn1,
               const float* __restrict__ Wn2, const float* __restrict__ bn2,
               const float* __restrict__ G, const float* __restrict__ Base,
               const unsigned short* __restrict__ w2h, const unsigned short* __restrict__ w2l,
               const unsigned short* __restrict__ w3h, const unsigned short* __restrict__ w3l,
               const unsigned short* __restrict__ w4h, const unsigned short* __restrict__ w4l,
               float* __restrict__ out)
{
  __shared__ unsigned short sAh[2 * 4096];   // act hi, ping/pong [j][k] swizzled
  __shared__ unsigned short sAl[2 * 4096];   // act lo
  __shared__ float sVecM[64][4];             // vec*mask per j
  __shared__ float sMask[64];
  __shared__ float sBase[64], sW1n[64], sHi[64], sXi[4];
  __shared__ float sHe[64], sCombP[4 * 48], sCN[32], sTmp[64], sHcomb[64];

  const int tid  = (int)threadIdx.x;
  const int blk  = (int)blockIdx.x;
  const int b    = blk >> 9;
  const int i    = blk & 511;
  const int lane = tid & 63;
  const int wid  = tid >> 6;
  const int l15  = lane & 15;
  const int lg   = lane >> 4;            // 0..3
  const int mb   = wid * 16;             // feat block (L2/C1)
  const int mb2  = (wid >> 1) * 16;      // coeff block (C2)

  if (tid < 64) {
    sBase[tid] = Base[((size_t)(b * NN + i)) * 64 + tid];
    sW1n[tid]  = We1[128 * 64 + tid];
    sHi[tid]   = h[((size_t)(b * NN + i)) * 64 + tid];
  }
  if (tid < 3) sXi[tid] = x[((size_t)(b * NN + i)) * 3 + tid];

  short8v w2hF[2], w2lF[2], w3hF[2], w3lF[2], w4hF[2], w4lF[2];
  #pragma unroll
  for (int ks = 0; ks < 2; ++ks) {
    const int ko = ks * 32 + lg * 8;
    w2hF[ks] = *(const short8v*)&w2h[(mb  + l15) * 64 + ko];
    w2lF[ks] = *(const short8v*)&w2l[(mb  + l15) * 64 + ko];
    w3hF[ks] = *(const short8v*)&w3h[(mb  + l15) * 64 + ko];
    w3lF[ks] = *(const short8v*)&w3l[(mb  + l15) * 64 + ko];
    w4hF[ks] = *(const short8v*)&w4h[(mb2 + l15) * 64 + ko];
    w4lF[ks] = *(const short8v*)&w4l[(mb2 + l15) * 64 + ko];
  }
  float be2v[4], bc1v[4], bc2v[4];
  #pragma unroll
  for (int r = 0; r < 4; ++r) {
    be2v[r] = be2[mb  + lg * 4 + r];
    bc1v[r] = bc1[mb  + lg * 4 + r];
    bc2v[r] = bc2[mb2 + lg * 4 + r];
  }

  float heAcc[4] = {0.f, 0.f, 0.f, 0.f};
  float cAcc[4][3] = {};

  for (int jt = 0; jt < 8; ++jt) {
    const int jb = jt * 64;
    __syncthreads();   // A: prev tile's C2 reads + sVecM reads done

    if (tid < 64) {    // geometry for this tile
      const int j = tid;
      const size_t xo = ((size_t)(b * NN + jb + j)) * 3;
      const float dx = x[xo + 0] - sXi[0];
      const float dy = x[xo + 1] - sXi[1];
      const float dz = x[xo + 2] - sXi[2];
      const float n2 = dx * dx + dy * dy + dz * dz;
      const float inv = __builtin_amdgcn_rcpf(n2 * n2 + 1e-10f);
      const float m = mask[((size_t)(b * NN + i)) * NN + jb + j];
      sVecM[j][0] = dx * inv * m; sVecM[j][1] = dy * inv * m; sVecM[j][2] = dz * inv * m;
      sMask[j] = m;
    }

    // ---- L1 elementwise: act1 = silu(G + Base + n2*We1n) -> buf0 ----
    {
      const int j = l15 + wid * 16;          // tile-local j (4 threads per j)
      const int jglob = jb + j;
      const size_t xo = ((size_t)(b * NN + jglob)) * 3;
      const float dx = x[xo + 0] - sXi[0];
      const float dy = x[xo + 1] - sXi[1];
      const float dz = x[xo + 2] - sXi[2];
      const float n2 = dx * dx + dy * dy + dz * dz;
      #pragma unroll
      for (int kk = 0; kk < 4; ++kk) {
        const int kb = lg * 16 + kk * 4;
        const float4 g4 = *(const float4*)&G[((size_t)(b * NN + jglob)) * 64 + kb];
        const float4 bs = *(const float4*)&sBase[kb];
        const float4 wn = *(const float4*)&sW1n[kb];
        const float v0 = silu_f(g4.x + bs.x + n2 * wn.x);
        const float v1 = silu_f(g4.y + bs.y + n2 * wn.y);
        const float v2 = silu_f(g4.z + bs.z + n2 * wn.z);
        const float v3 = silu_f(g4.w + bs.w + n2 * wn.w);
        split_store4(sAh, sAl, AIDX(j, kb), v0, v1, v2, v3);
      }
    }
    __syncthreads();   // B: buf0 + geometry ready

    // ---- L2: act2 = silu(act1 @ We2 + be2) -> buf1 ; h_e accum ----
    #pragma unroll
    for (int nf = 0; nf < 4; ++nf) {
      const int jn = nf * 16 + l15;
      f32x4 acc = { be2v[0], be2v[1], be2v[2], be2v[3] };
      #pragma unroll
      for (int ks = 0; ks < 2; ++ks) {
        const int kb = ks * 32 + lg * 8;
        const short8v bh = *(const short8v*)&sAh[AIDX(jn, kb)];
        const short8v bl = *(const short8v*)&sAl[AIDX(jn, kb)];
        acc = __builtin_amdgcn_mfma_f32_16x16x32_bf16(w2hF[ks], bh, acc, 0, 0, 0);
        acc = __builtin_amdgcn_mfma_f32_16x16x32_bf16(w2hF[ks], bl, acc, 0, 0, 0);
        acc = __builtin_amdgcn_mfma_f32_16x16x32_bf16(w2lF[ks], bh, acc, 0, 0, 0);
      }
      const float m = sMask[jn];
      float v[4];
      #pragma unroll
      for (int r = 0; r < 4; ++r) { v[r] = silu_f(acc[r]); heAcc[r] = fmaf(v[r], m, heAcc[r]); }
      split_store4(sAh, sAl, 4096 + AIDX(jn, mb + lg * 4), v[0], v[1], v[2], v[3]);
    }
    __syncthreads();   // C: buf1 ready (all buf0 reads done)

    // ---- C1: act3 = silu(act2 @ Wc1 + bc1) -> buf0 ----
    #pragma unroll
    for (int nf = 0; nf < 4; ++nf) {
      const int jn = nf * 16 + l15;
      f32x4 acc = { bc1v[0], bc1v[1], bc1v[2], bc1v[3] };
      #pragma unroll
      for (int ks = 0; ks < 2; ++ks) {
        const int kb = ks * 32 + lg * 8;
        const short8v bh = *(const short8v*)&sAh[4096 + AIDX(jn, kb)];
        const short8v bl = *(const short8v*)&sAl[4096 + AIDX(jn, kb)];
        acc = __builtin_amdgcn_mfma_f32_16x16x32_bf16(w3hF[ks], bh, acc, 0, 0, 0);
        acc = __builtin_amdgcn_mfma_f32_16x16x32_bf16(w3hF[ks], bl, acc, 0, 0, 0);
        acc = __builtin_amdgcn_mfma_f32_16x16x32_bf16(w3lF[ks], bh, acc, 0, 0, 0);
      }
      float v[4];
      #pragma unroll
      for (int r = 0; r < 4; ++r) v[r] = silu_f(acc[r]);
      split_store4(sAh, sAl, AIDX(jn, mb + lg * 4), v[0], v[1], v[2], v[3]);
    }
    __syncthreads();   // D: buf0(act3) ready

    // ---- C2: coeff = act3 @ Wc2 + bc2 ; comb accumulation ----
    #pragma unroll
    for (int nf = 0; nf < 2; ++nf) {
      const int jn = (wid & 1) * 32 + nf * 16 + l15;
      f32x4 acc = { bc2v[0], bc2v[1], bc2v[2], bc2v[3] };
      #pragma unroll
      for (int ks = 0; ks < 2; ++ks) {
        const int kb = ks * 32 + lg * 8;
        const short8v bh = *(const short8v*)&sAh[AIDX(jn, kb)];
        const short8v bl = *(const short8v*)&sAl[AIDX(jn, kb)];
        acc = __builtin_amdgcn_mfma_f32_16x16x32_bf16(w4hF[ks], bh, acc, 0, 0, 0);
        acc = __builtin_amdgcn_mfma_f32_16x16x32_bf16(w4hF[ks], bl, acc, 0, 0, 0);
        acc = __builtin_amdgcn_mfma_f32_16x16x32_bf16(w4lF[ks], bh, acc, 0, 0, 0);
      }
      const float vm0 = sVecM[jn][0], vm1 = sVecM[jn][1], vm2 = sVecM[jn][2];
      #pragma unroll
      for (int r = 0; r < 4; ++r) {
        cAcc[r][0] = fmaf(acc[r], vm0, cAcc[r][0]);
        cAcc[r][1] = fmaf(acc[r], vm1, cAcc[r][1]);
        cAcc[r][2] = fmaf(acc[r], vm2, cAcc[r][2]);
      }
    }
  }

  // -------- reductions --------
  #pragma unroll
  for (int r = 0; r < 4; ++r) {
    float s = heAcc[r];
    s += __shfl_xor(s, 1); s += __shfl_xor(s, 2); s += __shfl_xor(s, 4); s += __shfl_xor(s, 8);
    if (l15 == 0) sHe[mb + lg * 4 + r] = s;
  }
  #pragma unroll
  for (int r = 0; r < 4; ++r)
    #pragma unroll
    for (int d = 0; d < 3; ++d) {
      float s = cAcc[r][d];
      s += __shfl_xor(s, 1); s += __shfl_xor(s, 2); s += __shfl_xor(s, 4); s += __shfl_xor(s, 8);
      if (l15 == 0) sCombP[wid * 48 + (lg * 4 + r) * 3 + d] = s;
    }
  __syncthreads();
  if (tid < 32) {
    const int c = tid, w0 = (c >> 4) * 2, cl = c & 15;
    const float s0 = sCombP[w0 * 48 + cl * 3 + 0] + sCombP[(w0 + 1) * 48 + cl * 3 + 0];
    const float s1 = sCombP[w0 * 48 + cl * 3 + 1] + sCombP[(w0 + 1) * 48 + cl * 3 + 1];
    const float s2 = sCombP[w0 * 48 + cl * 3 + 2] + sCombP[(w0 + 1) * 48 + cl * 3 + 2];
    sCN[c] = s0 * s0 + s1 * s1 + s2 * s2;
  }
  __syncthreads();

  // -------- epilogue MLPs (fp32, tiny) --------
  if (tid < 64) {
    float s = bp1[tid];
    #pragma unroll 8
    for (int c = 0; c < 32; ++c) s = fmaf(sCN[c], Wp1[c * 64 + tid], s);
    sTmp[tid] = silu_f(s);
  }
  __syncthreads();
  if (tid < 64) {
    float s = bp2[tid];
    #pragma unroll 16
    for (int k = 0; k < 64; ++k) s = fmaf(sTmp[k], Wp2[k * 64 + tid], s);
    sHcomb[tid] = s;
  }
  __syncthreads();
  if (tid < 64) {
    float s = bn1[tid];
    #pragma unroll 16
    for (int m = 0; m < 64; ++m) s = fmaf(sHi[m],    Wn1[m * 64 + tid],         s);
    #pragma unroll 16
    for (int m = 0; m < 64; ++m) s = fmaf(sHe[m],    Wn1[(64 + m) * 64 + tid],  s);
    #pragma unroll 16
    for (int m = 0; m < 64; ++m) s = fmaf(sHcomb[m], Wn1[(128 + m) * 64 + tid], s);
    sTmp[tid] = silu_f(s);
  }
  __syncthreads();
  if (tid < 64) {
    float s = bn2[tid];
    #pragma unroll 16
    for (int k = 0; k < 64; ++k) s = fmaf(sTmp[k], Wn2[k * 64 + tid], s);
    out[((size_t)(b * NN + i)) * 64 + tid] = sHi[tid] + s;
  } else if (tid < 67) {
    const int d = tid - 64;
    out[(size_t)BB * NN * FF + ((size_t)(b * NN + i)) * 3 + d] = x[((size_t)(b * NN + i)) * 3 + d];
  }
}

extern "C" void kernel_launch(void* const* d_in, const int* in_sizes, int n_in,
                              void* d_out, int out_size, void* d_ws, size_t ws_size,
                              hipStream_t stream) {
  const float* h    = (const float*)d_in[0];
  const float* x    = (const float*)d_in[1];
  const float* mask = (const float*)d_in[2];
  const float* We1  = (const float*)d_in[3];
  const float* be1  = (const float*)d_in[4];
  const float* We2  = (const float*)d_in[5];
  const float* be2  = (const float*)d_in[6];
  const float* Wc1  = (const float*)d_in[7];
  const float* bc1  = (const float*)d_in[8];
  const float* Wc2  = (const float*)d_in[9];
  const float* bc2  = (const float*)d_in[10];
  const float* Wp1  = (const float*)d_in[11];
  const float* bp1  = (const float*)d_in[12];
  const float* Wp2  = (const float*)d_in[13];
  const float* bp2  = (const float*)d_in[14];
  const float* Wn1  = (const float*)d_in[15];
  const float* bn1  = (const float*)d_in[16];
  const float* Wn2  = (const float*)d_in[17];
  const float* bn2  = (const float*)d_in[18];
  float* out = (float*)d_out;

  float* G    = (float*)d_ws;                       // 2048*64 f32
  float* Base = G + 2048 * 64;                      // 2048*64 f32
  unsigned short* w2h = (unsigned short*)(Base + 2048 * 64);
  unsigned short* w2l = w2h + 4096;
  unsigned short* w3h = w2l + 4096;
  unsigned short* w3l = w3h + 4096;
  unsigned short* w4h = w3l + 4096;
  unsigned short* w4l = w4h + 2048;

  hipLaunchKernelGGL(sake_prep, dim3(65), dim3(256), 0, stream,
                     h, We1, be1, We2, Wc1, Wc2, G, Base,
                     w2h, w2l, w3h, w3l, w4h, w4l);
  hipLaunchKernelGGL(sake_mfma, dim3(BB * NN), dim3(256), 0, stream,
                     h, x, mask, We1, be2, bc1, bc2,
                     Wp1, bp1, Wp2, bp2, Wn1, bn1, Wn2, bn2,
                     G, Base, w2h, w2l, w3h, w3l, w4h, w4l, out);
}

// Round 4
// 154.026 us; speedup vs baseline: 3.4231x; 1.0487x over previous
//
#include <hip/hip_runtime.h>

#define BB 4
#define NN 512
#define FF 64

typedef __attribute__((ext_vector_type(8))) short short8v;   // 8 bf16 = 4 VGPR
typedef __attribute__((ext_vector_type(4))) float f32x4;

__device__ __forceinline__ float silu_f(float v) {
  // raw v_rcp_f32 instead of IEEE divide chain; ~1 ulp, fine at our threshold
  return v * __builtin_amdgcn_rcpf(1.0f + __expf(-v));
}
__device__ __forceinline__ unsigned short f2bf(float f) {
  unsigned int u = __float_as_uint(f);
  unsigned int r = (u + 0x7FFFu + ((u >> 16) & 1u)) >> 16;   // RNE (prep kernel only)
  return (unsigned short)r;
}
__device__ __forceinline__ float bf2f(unsigned short s) {
  return __uint_as_float(((unsigned int)s) << 16);
}
// packed f32x2 -> bf16x2 (RNE), low16 = a
__device__ __forceinline__ unsigned cvt_pk_bf16(float a, float b) {
  unsigned r;
  asm("v_cvt_pk_bf16_f32 %0, %1, %2" : "=v"(r) : "v"(a), "v"(b));
  return r;
}

// act LDS addressing: [j][k] bf16 rows of 128B, 16B slots XOR-swizzled by j.
#define AIDX(j, k) ((((j) << 6)) | (((((k) >> 3) ^ ((j) & 7))) << 3) | ((k) & 7))

// ---------------- prep kernel ----------------
// wg 0..63: G[b,j,o] = h_j @ We1[0:64];  Base[b,i,o] = be1 + h_i @ We1[64:128]
// wg 64   : split-transpose weights -> Wt{2,3,4}{hi,lo}[out][in] bf16
__global__ void sake_prep(const float* __restrict__ h, const float* __restrict__ We1,
                          const float* __restrict__ be1, const float* __restrict__ We2,
                          const float* __restrict__ Wc1, const float* __restrict__ Wc2,
                          float* __restrict__ G, float* __restrict__ Base,
                          unsigned short* __restrict__ w2h, unsigned short* __restrict__ w2l,
                          unsigned short* __restrict__ w3h, unsigned short* __restrict__ w3l,
                          unsigned short* __restrict__ w4h, unsigned short* __restrict__ w4l)
{
  const int wg = (int)blockIdx.x, tid = (int)threadIdx.x;
  if (wg < 64) {
    __shared__ float sH[32][64];
    const int r0 = wg * 32;
    for (int idx = tid; idx < 2048; idx += 256) sH[idx >> 6][idx & 63] = h[r0 * 64 + idx];
    __syncthreads();
    const int rl = tid >> 3;          // row 0..31
    const int o0 = (tid & 7) * 8;     // 8 outputs
    float aG[8], aB[8];
    #pragma unroll
    for (int o = 0; o < 8; ++o) { aG[o] = 0.f; aB[o] = be1[o0 + o]; }
    for (int k = 0; k < 64; ++k) {
      const float hv = sH[rl][k];
      const float4 g0 = *(const float4*)&We1[k * 64 + o0];
      const float4 g1 = *(const float4*)&We1[k * 64 + o0 + 4];
      const float4 b0 = *(const float4*)&We1[(64 + k) * 64 + o0];
      const float4 b1 = *(const float4*)&We1[(64 + k) * 64 + o0 + 4];
      aG[0] = fmaf(hv, g0.x, aG[0]); aG[1] = fmaf(hv, g0.y, aG[1]);
      aG[2] = fmaf(hv, g0.z, aG[2]); aG[3] = fmaf(hv, g0.w, aG[3]);
      aG[4] = fmaf(hv, g1.x, aG[4]); aG[5] = fmaf(hv, g1.y, aG[5]);
      aG[6] = fmaf(hv, g1.z, aG[6]); aG[7] = fmaf(hv, g1.w, aG[7]);
      aB[0] = fmaf(hv, b0.x, aB[0]); aB[1] = fmaf(hv, b0.y, aB[1]);
      aB[2] = fmaf(hv, b0.z, aB[2]); aB[3] = fmaf(hv, b0.w, aB[3]);
      aB[4] = fmaf(hv, b1.x, aB[4]); aB[5] = fmaf(hv, b1.y, aB[5]);
      aB[6] = fmaf(hv, b1.z, aB[6]); aB[7] = fmaf(hv, b1.w, aB[7]);
    }
    const size_t base = (size_t)(r0 + rl) * 64 + o0;
    *(float4*)&G[base]        = make_float4(aG[0], aG[1], aG[2], aG[3]);
    *(float4*)&G[base + 4]    = make_float4(aG[4], aG[5], aG[6], aG[7]);
    *(float4*)&Base[base]     = make_float4(aB[0], aB[1], aB[2], aB[3]);
    *(float4*)&Base[base + 4] = make_float4(aB[4], aB[5], aB[6], aB[7]);
  } else {
    for (int idx = tid; idx < 10240; idx += 256) {
      float w; unsigned short *ph, *pl; int pos;
      if (idx < 4096)      { const int o = idx >> 6,          k = idx & 63;
                             w = We2[k * 64 + o]; ph = w2h; pl = w2l; pos = o * 64 + k; }
      else if (idx < 8192) { const int t = idx - 4096, o = t >> 6, k = t & 63;
                             w = Wc1[k * 64 + o]; ph = w3h; pl = w3l; pos = o * 64 + k; }
      else                 { const int t = idx - 8192, c = t >> 6, k = t & 63;
                             w = Wc2[k * 32 + c]; ph = w4h; pl = w4l; pos = c * 64 + k; }
      const unsigned short hi = f2bf(w);
      const unsigned short lo = f2bf(w - bf2f(hi));
      ph[pos] = hi; pl[pos] = lo;
    }
  }
}

// split 4 f32 -> hi/lo packed pairs, store to LDS at element index a
__device__ __forceinline__ void split_store4(unsigned short* sAh, unsigned short* sAl,
                                             int a, float v0, float v1, float v2, float v3) {
  const unsigned uh01 = cvt_pk_bf16(v0, v1);
  const unsigned uh23 = cvt_pk_bf16(v2, v3);
  const float h0f = __uint_as_float(uh01 << 16);
  const float h1f = __uint_as_float(uh01 & 0xFFFF0000u);
  const float h2f = __uint_as_float(uh23 << 16);
  const float h3f = __uint_as_float(uh23 & 0xFFFF0000u);
  const unsigned ul01 = cvt_pk_bf16(v0 - h0f, v1 - h1f);
  const unsigned ul23 = cvt_pk_bf16(v2 - h2f, v3 - h3f);
  *(uint2*)&sAh[a] = make_uint2(uh01, uh23);
  *(uint2*)&sAl[a] = make_uint2(ul01, ul23);
}

// ---------------- main kernel ----------------
// __launch_bounds__(256, 4): 4 waves/EU -> 4 blocks/CU co-resident.
// LDS 36.9KB x 4 = 147.5KB <= 160KB; VGPR 96 <= 128 cap. Doubles the wave
// pool available to hide the per-tile barrier chain (4 barriers x 8 tiles).
__global__ __launch_bounds__(256, 4)
void sake_mfma(const float* __restrict__ h, const float* __restrict__ x,
               const float* __restrict__ mask,
               const float* __restrict__ We1, const float* __restrict__ be2,
               const float* __restrict__ bc1, const float* __restrict__ bc2,
               const float* __restrict__ Wp1, const float* __restrict__ bp1,
               const float* __restrict__ Wp2, const float* __restrict__ bp2,
               const float* __restrict__ Wn1, const float* __restrict__ bn1,
               const float* __restrict__ Wn2, const float* __restrict__ bn2,
               const float* __restrict__ G, const float* __restrict__ Base,
               const unsigned short* __restrict__ w2h, const unsigned short* __restrict__ w2l,
               const unsigned short* __restrict__ w3h, const unsigned short* __restrict__ w3l,
               const unsigned short* __restrict__ w4h, const unsigned short* __restrict__ w4l,
               float* __restrict__ out)
{
  __shared__ unsigned short sAh[2 * 4096];   // act hi, ping/pong [j][k] swizzled
  __shared__ unsigned short sAl[2 * 4096];   // act lo
  __shared__ float sVecM[64][4];             // vec*mask per j
  __shared__ float sMask[64];
  __shared__ float sBase[64], sW1n[64], sHi[64], sXi[4];
  __shared__ float sHe[64], sCombP[4 * 48], sCN[32], sTmp[64], sHcomb[64];

  const int tid  = (int)threadIdx.x;
  const int blk  = (int)blockIdx.x;
  const int b    = blk >> 9;
  const int i    = blk & 511;
  const int lane = tid & 63;
  const int wid  = tid >> 6;
  const int l15  = lane & 15;
  const int lg   = lane >> 4;            // 0..3
  const int mb   = wid * 16;             // feat block (L2/C1)
  const int mb2  = (wid >> 1) * 16;      // coeff block (C2)

  if (tid < 64) {
    sBase[tid] = Base[((size_t)(b * NN + i)) * 64 + tid];
    sW1n[tid]  = We1[128 * 64 + tid];
    sHi[tid]   = h[((size_t)(b * NN + i)) * 64 + tid];
  }
  if (tid < 3) sXi[tid] = x[((size_t)(b * NN + i)) * 3 + tid];

  short8v w2hF[2], w2lF[2], w3hF[2], w3lF[2], w4hF[2], w4lF[2];
  #pragma unroll
  for (int ks = 0; ks < 2; ++ks) {
    const int ko = ks * 32 + lg * 8;
    w2hF[ks] = *(const short8v*)&w2h[(mb  + l15) * 64 + ko];
    w2lF[ks] = *(const short8v*)&w2l[(mb  + l15) * 64 + ko];
    w3hF[ks] = *(const short8v*)&w3h[(mb  + l15) * 64 + ko];
    w3lF[ks] = *(const short8v*)&w3l[(mb  + l15) * 64 + ko];
    w4hF[ks] = *(const short8v*)&w4h[(mb2 + l15) * 64 + ko];
    w4lF[ks] = *(const short8v*)&w4l[(mb2 + l15) * 64 + ko];
  }
  float be2v[4], bc1v[4], bc2v[4];
  #pragma unroll
  for (int r = 0; r < 4; ++r) {
    be2v[r] = be2[mb  + lg * 4 + r];
    bc1v[r] = bc1[mb  + lg * 4 + r];
    bc2v[r] = bc2[mb2 + lg * 4 + r];
  }

  float heAcc[4] = {0.f, 0.f, 0.f, 0.f};
  float cAcc[4][3] = {};

  for (int jt = 0; jt < 8; ++jt) {
    const int jb = jt * 64;
    __syncthreads();   // A: prev tile's C2 reads + sVecM reads done

    if (tid < 64) {    // geometry for this tile
      const int j = tid;
      const size_t xo = ((size_t)(b * NN + jb + j)) * 3;
      const float dx = x[xo + 0] - sXi[0];
      const float dy = x[xo + 1] - sXi[1];
      const float dz = x[xo + 2] - sXi[2];
      const float n2 = dx * dx + dy * dy + dz * dz;
      const float inv = __builtin_amdgcn_rcpf(n2 * n2 + 1e-10f);
      const float m = mask[((size_t)(b * NN + i)) * NN + jb + j];
      sVecM[j][0] = dx * inv * m; sVecM[j][1] = dy * inv * m; sVecM[j][2] = dz * inv * m;
      sMask[j] = m;
    }

    // ---- L1 elementwise: act1 = silu(G + Base + n2*We1n) -> buf0 ----
    {
      const int j = l15 + wid * 16;          // tile-local j (4 threads per j)
      const int jglob = jb + j;
      const size_t xo = ((size_t)(b * NN + jglob)) * 3;
      const float dx = x[xo + 0] - sXi[0];
      const float dy = x[xo + 1] - sXi[1];
      const float dz = x[xo + 2] - sXi[2];
      const float n2 = dx * dx + dy * dy + dz * dz;
      #pragma unroll
      for (int kk = 0; kk < 4; ++kk) {
        const int kb = lg * 16 + kk * 4;
        const float4 g4 = *(const float4*)&G[((size_t)(b * NN + jglob)) * 64 + kb];
        const float4 bs = *(const float4*)&sBase[kb];
        const float4 wn = *(const float4*)&sW1n[kb];
        const float v0 = silu_f(g4.x + bs.x + n2 * wn.x);
        const float v1 = silu_f(g4.y + bs.y + n2 * wn.y);
        const float v2 = silu_f(g4.z + bs.z + n2 * wn.z);
        const float v3 = silu_f(g4.w + bs.w + n2 * wn.w);
        split_store4(sAh, sAl, AIDX(j, kb), v0, v1, v2, v3);
      }
    }
    __syncthreads();   // B: buf0 + geometry ready

    // ---- L2: act2 = silu(act1 @ We2 + be2) -> buf1 ; h_e accum ----
    #pragma unroll
    for (int nf = 0; nf < 4; ++nf) {
      const int jn = nf * 16 + l15;
      f32x4 acc = { be2v[0], be2v[1], be2v[2], be2v[3] };
      #pragma unroll
      for (int ks = 0; ks < 2; ++ks) {
        const int kb = ks * 32 + lg * 8;
        const short8v bh = *(const short8v*)&sAh[AIDX(jn, kb)];
        const short8v bl = *(const short8v*)&sAl[AIDX(jn, kb)];
        acc = __builtin_amdgcn_mfma_f32_16x16x32_bf16(w2hF[ks], bh, acc, 0, 0, 0);
        acc = __builtin_amdgcn_mfma_f32_16x16x32_bf16(w2hF[ks], bl, acc, 0, 0, 0);
        acc = __builtin_amdgcn_mfma_f32_16x16x32_bf16(w2lF[ks], bh, acc, 0, 0, 0);
      }
      const float m = sMask[jn];
      float v[4];
      #pragma unroll
      for (int r = 0; r < 4; ++r) { v[r] = silu_f(acc[r]); heAcc[r] = fmaf(v[r], m, heAcc[r]); }
      split_store4(sAh, sAl, 4096 + AIDX(jn, mb + lg * 4), v[0], v[1], v[2], v[3]);
    }
    __syncthreads();   // C: buf1 ready (all buf0 reads done)

    // ---- C1: act3 = silu(act2 @ Wc1 + bc1) -> buf0 ----
    #pragma unroll
    for (int nf = 0; nf < 4; ++nf) {
      const int jn = nf * 16 + l15;
      f32x4 acc = { bc1v[0], bc1v[1], bc1v[2], bc1v[3] };
      #pragma unroll
      for (int ks = 0; ks < 2; ++ks) {
        const int kb = ks * 32 + lg * 8;
        const short8v bh = *(const short8v*)&sAh[4096 + AIDX(jn, kb)];
        const short8v bl = *(const short8v*)&sAl[4096 + AIDX(jn, kb)];
        acc = __builtin_amdgcn_mfma_f32_16x16x32_bf16(w3hF[ks], bh, acc, 0, 0, 0);
        acc = __builtin_amdgcn_mfma_f32_16x16x32_bf16(w3hF[ks], bl, acc, 0, 0, 0);
        acc = __builtin_amdgcn_mfma_f32_16x16x32_bf16(w3lF[ks], bh, acc, 0, 0, 0);
      }
      float v[4];
      #pragma unroll
      for (int r = 0; r < 4; ++r) v[r] = silu_f(acc[r]);
      split_store4(sAh, sAl, AIDX(jn, mb + lg * 4), v[0], v[1], v[2], v[3]);
    }
    __syncthreads();   // D: buf0(act3) ready

    // ---- C2: coeff = act3 @ Wc2 + bc2 ; comb accumulation ----
    #pragma unroll
    for (int nf = 0; nf < 2; ++nf) {
      const int jn = (wid & 1) * 32 + nf * 16 + l15;
      f32x4 acc = { bc2v[0], bc2v[1], bc2v[2], bc2v[3] };
      #pragma unroll
      for (int ks = 0; ks < 2; ++ks) {
        const int kb = ks * 32 + lg * 8;
        const short8v bh = *(const short8v*)&sAh[AIDX(jn, kb)];
        const short8v bl = *(const short8v*)&sAl[AIDX(jn, kb)];
        acc = __builtin_amdgcn_mfma_f32_16x16x32_bf16(w4hF[ks], bh, acc, 0, 0, 0);
        acc = __builtin_amdgcn_mfma_f32_16x16x32_bf16(w4hF[ks], bl, acc, 0, 0, 0);
        acc = __builtin_amdgcn_mfma_f32_16x16x32_bf16(w4lF[ks], bh, acc, 0, 0, 0);
      }
      const float vm0 = sVecM[jn][0], vm1 = sVecM[jn][1], vm2 = sVecM[jn][2];
      #pragma unroll
      for (int r = 0; r < 4; ++r) {
        cAcc[r][0] = fmaf(acc[r], vm0, cAcc[r][0]);
        cAcc[r][1] = fmaf(acc[r], vm1, cAcc[r][1]);
        cAcc[r][2] = fmaf(acc[r], vm2, cAcc[r][2]);
      }
    }
  }

  // -------- reductions --------
  #pragma unroll
  for (int r = 0; r < 4; ++r) {
    float s = heAcc[r];
    s += __shfl_xor(s, 1); s += __shfl_xor(s, 2); s += __shfl_xor(s, 4); s += __shfl_xor(s, 8);
    if (l15 == 0) sHe[mb + lg * 4 + r] = s;
  }
  #pragma unroll
  for (int r = 0; r < 4; ++r)
    #pragma unroll
    for (int d = 0; d < 3; ++d) {
      float s = cAcc[r][d];
      s += __shfl_xor(s, 1); s += __shfl_xor(s, 2); s += __shfl_xor(s, 4); s += __shfl_xor(s, 8);
      if (l15 == 0) sCombP[wid * 48 + (lg * 4 + r) * 3 + d] = s;
    }
  __syncthreads();
  if (tid < 32) {
    const int c = tid, w0 = (c >> 4) * 2, cl = c & 15;
    const float s0 = sCombP[w0 * 48 + cl * 3 + 0] + sCombP[(w0 + 1) * 48 + cl * 3 + 0];
    const float s1 = sCombP[w0 * 48 + cl * 3 + 1] + sCombP[(w0 + 1) * 48 + cl * 3 + 1];
    const float s2 = sCombP[w0 * 48 + cl * 3 + 2] + sCombP[(w0 + 1) * 48 + cl * 3 + 2];
    sCN[c] = s0 * s0 + s1 * s1 + s2 * s2;
  }
  __syncthreads();

  // -------- epilogue MLPs (fp32, tiny) --------
  if (tid < 64) {
    float s = bp1[tid];
    #pragma unroll 8
    for (int c = 0; c < 32; ++c) s = fmaf(sCN[c], Wp1[c * 64 + tid], s);
    sTmp[tid] = silu_f(s);
  }
  __syncthreads();
  if (tid < 64) {
    float s = bp2[tid];
    #pragma unroll 16
    for (int k = 0; k < 64; ++k) s = fmaf(sTmp[k], Wp2[k * 64 + tid], s);
    sHcomb[tid] = s;
  }
  __syncthreads();
  if (tid < 64) {
    float s = bn1[tid];
    #pragma unroll 16
    for (int m = 0; m < 64; ++m) s = fmaf(sHi[m],    Wn1[m * 64 + tid],         s);
    #pragma unroll 16
    for (int m = 0; m < 64; ++m) s = fmaf(sHe[m],    Wn1[(64 + m) * 64 + tid],  s);
    #pragma unroll 16
    for (int m = 0; m < 64; ++m) s = fmaf(sHcomb[m], Wn1[(128 + m) * 64 + tid], s);
    sTmp[tid] = silu_f(s);
  }
  __syncthreads();
  if (tid < 64) {
    float s = bn2[tid];
    #pragma unroll 16
    for (int k = 0; k < 64; ++k) s = fmaf(sTmp[k], Wn2[k * 64 + tid], s);
    out[((size_t)(b * NN + i)) * 64 + tid] = sHi[tid] + s;
  } else if (tid < 67) {
    const int d = tid - 64;
    out[(size_t)BB * NN * FF + ((size_t)(b * NN + i)) * 3 + d] = x[((size_t)(b * NN + i)) * 3 + d];
  }
}

extern "C" void kernel_launch(void* const* d_in, const int* in_sizes, int n_in,
                              void* d_out, int out_size, void* d_ws, size_t ws_size,
                              hipStream_t stream) {
  const float* h    = (const float*)d_in[0];
  const float* x    = (const float*)d_in[1];
  const float* mask = (const float*)d_in[2];
  const float* We1  = (const float*)d_in[3];
  const float* be1  = (const float*)d_in[4];
  const float* We2  = (const float*)d_in[5];
  const float* be2  = (const float*)d_in[6];
  const float* Wc1  = (const float*)d_in[7];
  const float* bc1  = (const float*)d_in[8];
  const float* Wc2  = (const float*)d_in[9];
  const float* bc2  = (const float*)d_in[10];
  const float* Wp1  = (const float*)d_in[11];
  const float* bp1  = (const float*)d_in[12];
  const float* Wp2  = (const float*)d_in[13];
  const float* bp2  = (const float*)d_in[14];
  const float* Wn1  = (const float*)d_in[15];
  const float* bn1  = (const float*)d_in[16];
  const float* Wn2  = (const float*)d_in[17];
  const float* bn2  = (const float*)d_in[18];
  float* out = (float*)d_out;

  float* G    = (float*)d_ws;                       // 2048*64 f32
  float* Base = G + 2048 * 64;                      // 2048*64 f32
  unsigned short* w2h = (unsigned short*)(Base + 2048 * 64);
  unsigned short* w2l = w2h + 4096;
  unsigned short* w3h = w2l + 4096;
  unsigned short* w3l = w3h + 4096;
  unsigned short* w4h = w3l + 4096;
  unsigned short* w4l = w4h + 2048;

  hipLaunchKernelGGL(sake_prep, dim3(65), dim3(256), 0, stream,
                     h, We1, be1, We2, Wc1, Wc2, G, Base,
                     w2h, w2l, w3h, w3l, w4h, w4l);
  hipLaunchKernelGGL(sake_mfma, dim3(BB * NN), dim3(256), 0, stream,
                     h, x, mask, We1, be2, bc1, bc2,
                     Wp1, bp1, Wp2, bp2, Wn1, bn1, Wn2, bn2,
                     G, Base, w2h, w2l, w3h, w3l, w4h, w4l, out);
}

// Round 5
// 127.344 us; speedup vs baseline: 4.1404x; 1.2095x over previous
//
#include <hip/hip_runtime.h>

#define BB 4
#define NN 512
#define FF 64

typedef __attribute__((ext_vector_type(8))) short short8v;   // 8 bf16 = 4 VGPR
typedef __attribute__((ext_vector_type(4))) float f32x4;

__device__ __forceinline__ float silu_f(float v) {
  // raw v_rcp_f32 instead of IEEE divide chain; ~1 ulp, fine at our threshold
  return v * __builtin_amdgcn_rcpf(1.0f + __expf(-v));
}
__device__ __forceinline__ unsigned short f2bf(float f) {
  unsigned int u = __float_as_uint(f);
  unsigned int r = (u + 0x7FFFu + ((u >> 16) & 1u)) >> 16;   // RNE (prep kernel only)
  return (unsigned short)r;
}
__device__ __forceinline__ float bf2f(unsigned short s) {
  return __uint_as_float(((unsigned int)s) << 16);
}
// packed f32x2 -> bf16x2 (RNE), low16 = a
__device__ __forceinline__ unsigned cvt_pk_bf16(float a, float b) {
  unsigned r;
  asm("v_cvt_pk_bf16_f32 %0, %1, %2" : "=v"(r) : "v"(a), "v"(b));
  return r;
}

// act LDS addressing: [j][k] bf16 rows of 128B, 16B slots XOR-swizzled by j.
#define AIDX(j, k) ((((j) << 6)) | (((((k) >> 3) ^ ((j) & 7))) << 3) | ((k) & 7))

// ---------------- prep kernel ----------------
// wg 0..63: G[b,j,o] = h_j @ We1[0:64];  Base[b,i,o] = be1 + h_i @ We1[64:128]
// wg 64   : split-transpose weights -> Wt{2,3,4}{hi,lo}[out][in] bf16
__global__ void sake_prep(const float* __restrict__ h, const float* __restrict__ We1,
                          const float* __restrict__ be1, const float* __restrict__ We2,
                          const float* __restrict__ Wc1, const float* __restrict__ Wc2,
                          float* __restrict__ G, float* __restrict__ Base,
                          unsigned short* __restrict__ w2h, unsigned short* __restrict__ w2l,
                          unsigned short* __restrict__ w3h, unsigned short* __restrict__ w3l,
                          unsigned short* __restrict__ w4h, unsigned short* __restrict__ w4l)
{
  const int wg = (int)blockIdx.x, tid = (int)threadIdx.x;
  if (wg < 64) {
    __shared__ float sH[32][64];
    const int r0 = wg * 32;
    for (int idx = tid; idx < 2048; idx += 256) sH[idx >> 6][idx & 63] = h[r0 * 64 + idx];
    __syncthreads();
    const int rl = tid >> 3;          // row 0..31
    const int o0 = (tid & 7) * 8;     // 8 outputs
    float aG[8], aB[8];
    #pragma unroll
    for (int o = 0; o < 8; ++o) { aG[o] = 0.f; aB[o] = be1[o0 + o]; }
    for (int k = 0; k < 64; ++k) {
      const float hv = sH[rl][k];
      const float4 g0 = *(const float4*)&We1[k * 64 + o0];
      const float4 g1 = *(const float4*)&We1[k * 64 + o0 + 4];
      const float4 b0 = *(const float4*)&We1[(64 + k) * 64 + o0];
      const float4 b1 = *(const float4*)&We1[(64 + k) * 64 + o0 + 4];
      aG[0] = fmaf(hv, g0.x, aG[0]); aG[1] = fmaf(hv, g0.y, aG[1]);
      aG[2] = fmaf(hv, g0.z, aG[2]); aG[3] = fmaf(hv, g0.w, aG[3]);
      aG[4] = fmaf(hv, g1.x, aG[4]); aG[5] = fmaf(hv, g1.y, aG[5]);
      aG[6] = fmaf(hv, g1.z, aG[6]); aG[7] = fmaf(hv, g1.w, aG[7]);
      aB[0] = fmaf(hv, b0.x, aB[0]); aB[1] = fmaf(hv, b0.y, aB[1]);
      aB[2] = fmaf(hv, b0.z, aB[2]); aB[3] = fmaf(hv, b0.w, aB[3]);
      aB[4] = fmaf(hv, b1.x, aB[4]); aB[5] = fmaf(hv, b1.y, aB[5]);
      aB[6] = fmaf(hv, b1.z, aB[6]); aB[7] = fmaf(hv, b1.w, aB[7]);
    }
    const size_t base = (size_t)(r0 + rl) * 64 + o0;
    *(float4*)&G[base]        = make_float4(aG[0], aG[1], aG[2], aG[3]);
    *(float4*)&G[base + 4]    = make_float4(aG[4], aG[5], aG[6], aG[7]);
    *(float4*)&Base[base]     = make_float4(aB[0], aB[1], aB[2], aB[3]);
    *(float4*)&Base[base + 4] = make_float4(aB[4], aB[5], aB[6], aB[7]);
  } else {
    for (int idx = tid; idx < 10240; idx += 256) {
      float w; unsigned short *ph, *pl; int pos;
      if (idx < 4096)      { const int o = idx >> 6,          k = idx & 63;
                             w = We2[k * 64 + o]; ph = w2h; pl = w2l; pos = o * 64 + k; }
      else if (idx < 8192) { const int t = idx - 4096, o = t >> 6, k = t & 63;
                             w = Wc1[k * 64 + o]; ph = w3h; pl = w3l; pos = o * 64 + k; }
      else                 { const int t = idx - 8192, c = t >> 6, k = t & 63;
                             w = Wc2[k * 32 + c]; ph = w4h; pl = w4l; pos = c * 64 + k; }
      const unsigned short hi = f2bf(w);
      const unsigned short lo = f2bf(w - bf2f(hi));
      ph[pos] = hi; pl[pos] = lo;
    }
  }
}

// pack 4 f32 -> 4 bf16 (hi only), store to LDS at element index a
__device__ __forceinline__ void pack_store4(unsigned short* sAh, int a,
                                            float v0, float v1, float v2, float v3) {
  *(uint2*)&sAh[a] = make_uint2(cvt_pk_bf16(v0, v1), cvt_pk_bf16(v2, v3));
}

// ---------------- main kernel ----------------
// Acts stored bf16 (hi only); weights 2-term hi/lo split. Products:
// (w_hi + w_lo) * a_hi  -> 2 MFMA per k-slice.
// __launch_bounds__(256, 3): VGPR cap 170 (no spill; unified VGPR+AGPR ~96+acc),
// 3 blocks/CU (LDS 20KB x 3 = 60KB).
__global__ __launch_bounds__(256, 3)
void sake_mfma(const float* __restrict__ h, const float* __restrict__ x,
               const float* __restrict__ mask,
               const float* __restrict__ We1, const float* __restrict__ be2,
               const float* __restrict__ bc1, const float* __restrict__ bc2,
               const float* __restrict__ Wp1, const float* __restrict__ bp1,
               const float* __restrict__ Wp2, const float* __restrict__ bp2,
               const float* __restrict__ Wn1, const float* __restrict__ bn1,
               const float* __restrict__ Wn2, const float* __restrict__ bn2,
               const float* __restrict__ G, const float* __restrict__ Base,
               const unsigned short* __restrict__ w2h, const unsigned short* __restrict__ w2l,
               const unsigned short* __restrict__ w3h, const unsigned short* __restrict__ w3l,
               const unsigned short* __restrict__ w4h, const unsigned short* __restrict__ w4l,
               float* __restrict__ out)
{
  __shared__ unsigned short sAh[2 * 4096];   // act bf16, ping/pong [j][k] swizzled
  __shared__ float sVecM[64][4];             // vec*mask per j
  __shared__ float sMask[64];
  __shared__ float sBase[64], sW1n[64], sHi[64], sXi[4];
  __shared__ float sHe[64], sCombP[4 * 48], sCN[32], sTmp[64], sHcomb[64];

  const int tid  = (int)threadIdx.x;
  const int blk  = (int)blockIdx.x;
  const int b    = blk >> 9;
  const int i    = blk & 511;
  const int lane = tid & 63;
  const int wid  = tid >> 6;
  const int l15  = lane & 15;
  const int lg   = lane >> 4;            // 0..3
  const int mb   = wid * 16;             // feat block (L2/C1)
  const int mb2  = (wid >> 1) * 16;      // coeff block (C2)

  if (tid < 64) {
    sBase[tid] = Base[((size_t)(b * NN + i)) * 64 + tid];
    sW1n[tid]  = We1[128 * 64 + tid];
    sHi[tid]   = h[((size_t)(b * NN + i)) * 64 + tid];
  }
  if (tid < 3) sXi[tid] = x[((size_t)(b * NN + i)) * 3 + tid];

  short8v w2hF[2], w2lF[2], w3hF[2], w3lF[2], w4hF[2], w4lF[2];
  #pragma unroll
  for (int ks = 0; ks < 2; ++ks) {
    const int ko = ks * 32 + lg * 8;
    w2hF[ks] = *(const short8v*)&w2h[(mb  + l15) * 64 + ko];
    w2lF[ks] = *(const short8v*)&w2l[(mb  + l15) * 64 + ko];
    w3hF[ks] = *(const short8v*)&w3h[(mb  + l15) * 64 + ko];
    w3lF[ks] = *(const short8v*)&w3l[(mb  + l15) * 64 + ko];
    w4hF[ks] = *(const short8v*)&w4h[(mb2 + l15) * 64 + ko];
    w4lF[ks] = *(const short8v*)&w4l[(mb2 + l15) * 64 + ko];
  }
  float be2v[4], bc1v[4], bc2v[4];
  #pragma unroll
  for (int r = 0; r < 4; ++r) {
    be2v[r] = be2[mb  + lg * 4 + r];
    bc1v[r] = bc1[mb  + lg * 4 + r];
    bc2v[r] = bc2[mb2 + lg * 4 + r];
  }

  float heAcc[4] = {0.f, 0.f, 0.f, 0.f};
  float cAcc[4][3] = {};

  for (int jt = 0; jt < 8; ++jt) {
    const int jb = jt * 64;
    __syncthreads();   // A: prev tile's C2 reads + sVecM reads done

    if (tid < 64) {    // geometry for this tile
      const int j = tid;
      const size_t xo = ((size_t)(b * NN + jb + j)) * 3;
      const float dx = x[xo + 0] - sXi[0];
      const float dy = x[xo + 1] - sXi[1];
      const float dz = x[xo + 2] - sXi[2];
      const float n2 = dx * dx + dy * dy + dz * dz;
      const float inv = __builtin_amdgcn_rcpf(n2 * n2 + 1e-10f);
      const float m = mask[((size_t)(b * NN + i)) * NN + jb + j];
      sVecM[j][0] = dx * inv * m; sVecM[j][1] = dy * inv * m; sVecM[j][2] = dz * inv * m;
      sMask[j] = m;
    }

    // ---- L1 elementwise: act1 = silu(G + Base + n2*We1n) -> buf0 ----
    {
      const int j = l15 + wid * 16;          // tile-local j (4 threads per j)
      const int jglob = jb + j;
      const size_t xo = ((size_t)(b * NN + jglob)) * 3;
      const float dx = x[xo + 0] - sXi[0];
      const float dy = x[xo + 1] - sXi[1];
      const float dz = x[xo + 2] - sXi[2];
      const float n2 = dx * dx + dy * dy + dz * dz;
      #pragma unroll
      for (int kk = 0; kk < 4; ++kk) {
        const int kb = lg * 16 + kk * 4;
        const float4 g4 = *(const float4*)&G[((size_t)(b * NN + jglob)) * 64 + kb];
        const float4 bs = *(const float4*)&sBase[kb];
        const float4 wn = *(const float4*)&sW1n[kb];
        const float v0 = silu_f(g4.x + bs.x + n2 * wn.x);
        const float v1 = silu_f(g4.y + bs.y + n2 * wn.y);
        const float v2 = silu_f(g4.z + bs.z + n2 * wn.z);
        const float v3 = silu_f(g4.w + bs.w + n2 * wn.w);
        pack_store4(sAh, AIDX(j, kb), v0, v1, v2, v3);
      }
    }
    __syncthreads();   // B: buf0 + geometry ready

    // ---- L2: act2 = silu(act1 @ We2 + be2) -> buf1 ; h_e accum ----
    #pragma unroll
    for (int nf = 0; nf < 4; ++nf) {
      const int jn = nf * 16 + l15;
      f32x4 acc = { be2v[0], be2v[1], be2v[2], be2v[3] };
      #pragma unroll
      for (int ks = 0; ks < 2; ++ks) {
        const int kb = ks * 32 + lg * 8;
        const short8v bh = *(const short8v*)&sAh[AIDX(jn, kb)];
        acc = __builtin_amdgcn_mfma_f32_16x16x32_bf16(w2hF[ks], bh, acc, 0, 0, 0);
        acc = __builtin_amdgcn_mfma_f32_16x16x32_bf16(w2lF[ks], bh, acc, 0, 0, 0);
      }
      const float m = sMask[jn];
      float v[4];
      #pragma unroll
      for (int r = 0; r < 4; ++r) { v[r] = silu_f(acc[r]); heAcc[r] = fmaf(v[r], m, heAcc[r]); }
      pack_store4(sAh, 4096 + AIDX(jn, mb + lg * 4), v[0], v[1], v[2], v[3]);
    }
    __syncthreads();   // C: buf1 ready (all buf0 reads done)

    // ---- C1: act3 = silu(act2 @ Wc1 + bc1) -> buf0 ----
    #pragma unroll
    for (int nf = 0; nf < 4; ++nf) {
      const int jn = nf * 16 + l15;
      f32x4 acc = { bc1v[0], bc1v[1], bc1v[2], bc1v[3] };
      #pragma unroll
      for (int ks = 0; ks < 2; ++ks) {
        const int kb = ks * 32 + lg * 8;
        const short8v bh = *(const short8v*)&sAh[4096 + AIDX(jn, kb)];
        acc = __builtin_amdgcn_mfma_f32_16x16x32_bf16(w3hF[ks], bh, acc, 0, 0, 0);
        acc = __builtin_amdgcn_mfma_f32_16x16x32_bf16(w3lF[ks], bh, acc, 0, 0, 0);
      }
      float v[4];
      #pragma unroll
      for (int r = 0; r < 4; ++r) v[r] = silu_f(acc[r]);
      pack_store4(sAh, AIDX(jn, mb + lg * 4), v[0], v[1], v[2], v[3]);
    }
    __syncthreads();   // D: buf0(act3) ready

    // ---- C2: coeff = act3 @ Wc2 + bc2 ; comb accumulation ----
    #pragma unroll
    for (int nf = 0; nf < 2; ++nf) {
      const int jn = (wid & 1) * 32 + nf * 16 + l15;
      f32x4 acc = { bc2v[0], bc2v[1], bc2v[2], bc2v[3] };
      #pragma unroll
      for (int ks = 0; ks < 2; ++ks) {
        const int kb = ks * 32 + lg * 8;
        const short8v bh = *(const short8v*)&sAh[AIDX(jn, kb)];
        acc = __builtin_amdgcn_mfma_f32_16x16x32_bf16(w4hF[ks], bh, acc, 0, 0, 0);
        acc = __builtin_amdgcn_mfma_f32_16x16x32_bf16(w4lF[ks], bh, acc, 0, 0, 0);
      }
      const float vm0 = sVecM[jn][0], vm1 = sVecM[jn][1], vm2 = sVecM[jn][2];
      #pragma unroll
      for (int r = 0; r < 4; ++r) {
        cAcc[r][0] = fmaf(acc[r], vm0, cAcc[r][0]);
        cAcc[r][1] = fmaf(acc[r], vm1, cAcc[r][1]);
        cAcc[r][2] = fmaf(acc[r], vm2, cAcc[r][2]);
      }
    }
  }

  // -------- reductions --------
  #pragma unroll
  for (int r = 0; r < 4; ++r) {
    float s = heAcc[r];
    s += __shfl_xor(s, 1); s += __shfl_xor(s, 2); s += __shfl_xor(s, 4); s += __shfl_xor(s, 8);
    if (l15 == 0) sHe[mb + lg * 4 + r] = s;
  }
  #pragma unroll
  for (int r = 0; r < 4; ++r)
    #pragma unroll
    for (int d = 0; d < 3; ++d) {
      float s = cAcc[r][d];
      s += __shfl_xor(s, 1); s += __shfl_xor(s, 2); s += __shfl_xor(s, 4); s += __shfl_xor(s, 8);
      if (l15 == 0) sCombP[wid * 48 + (lg * 4 + r) * 3 + d] = s;
    }
  __syncthreads();
  if (tid < 32) {
    const int c = tid, w0 = (c >> 4) * 2, cl = c & 15;
    const float s0 = sCombP[w0 * 48 + cl * 3 + 0] + sCombP[(w0 + 1) * 48 + cl * 3 + 0];
    const float s1 = sCombP[w0 * 48 + cl * 3 + 1] + sCombP[(w0 + 1) * 48 + cl * 3 + 1];
    const float s2 = sCombP[w0 * 48 + cl * 3 + 2] + sCombP[(w0 + 1) * 48 + cl * 3 + 2];
    sCN[c] = s0 * s0 + s1 * s1 + s2 * s2;
  }
  __syncthreads();

  // -------- epilogue MLPs (fp32, tiny) --------
  if (tid < 64) {
    float s = bp1[tid];
    #pragma unroll 8
    for (int c = 0; c < 32; ++c) s = fmaf(sCN[c], Wp1[c * 64 + tid], s);
    sTmp[tid] = silu_f(s);
  }
  __syncthreads();
  if (tid < 64) {
    float s = bp2[tid];
    #pragma unroll 16
    for (int k = 0; k < 64; ++k) s = fmaf(sTmp[k], Wp2[k * 64 + tid], s);
    sHcomb[tid] = s;
  }
  __syncthreads();
  if (tid < 64) {
    float s = bn1[tid];
    #pragma unroll 16
    for (int m = 0; m < 64; ++m) s = fmaf(sHi[m],    Wn1[m * 64 + tid],         s);
    #pragma unroll 16
    for (int m = 0; m < 64; ++m) s = fmaf(sHe[m],    Wn1[(64 + m) * 64 + tid],  s);
    #pragma unroll 16
    for (int m = 0; m < 64; ++m) s = fmaf(sHcomb[m], Wn1[(128 + m) * 64 + tid], s);
    sTmp[tid] = silu_f(s);
  }
  __syncthreads();
  if (tid < 64) {
    float s = bn2[tid];
    #pragma unroll 16
    for (int k = 0; k < 64; ++k) s = fmaf(sTmp[k], Wn2[k * 64 + tid], s);
    out[((size_t)(b * NN + i)) * 64 + tid] = sHi[tid] + s;
  } else if (tid < 67) {
    const int d = tid - 64;
    out[(size_t)BB * NN * FF + ((size_t)(b * NN + i)) * 3 + d] = x[((size_t)(b * NN + i)) * 3 + d];
  }
}

extern "C" void kernel_launch(void* const* d_in, const int* in_sizes, int n_in,
                              void* d_out, int out_size, void* d_ws, size_t ws_size,
                              hipStream_t stream) {
  const float* h    = (const float*)d_in[0];
  const float* x    = (const float*)d_in[1];
  const float* mask = (const float*)d_in[2];
  const float* We1  = (const float*)d_in[3];
  const float* be1  = (const float*)d_in[4];
  const float* We2  = (const float*)d_in[5];
  const float* be2  = (const float*)d_in[6];
  const float* Wc1  = (const float*)d_in[7];
  const float* bc1  = (const float*)d_in[8];
  const float* Wc2  = (const float*)d_in[9];
  const float* bc2  = (const float*)d_in[10];
  const float* Wp1  = (const float*)d_in[11];
  const float* bp1  = (const float*)d_in[12];
  const float* Wp2  = (const float*)d_in[13];
  const float* bp2  = (const float*)d_in[14];
  const float* Wn1  = (const float*)d_in[15];
  const float* bn1  = (const float*)d_in[16];
  const float* Wn2  = (const float*)d_in[17];
  const float* bn2  = (const float*)d_in[18];
  float* out = (float*)d_out;

  float* G    = (float*)d_ws;                       // 2048*64 f32
  float* Base = G + 2048 * 64;                      // 2048*64 f32
  unsigned short* w2h = (unsigned short*)(Base + 2048 * 64);
  unsigned short* w2l = w2h + 4096;
  unsigned short* w3h = w2l + 4096;
  unsigned short* w3l = w3h + 4096;
  unsigned short* w4h = w3l + 4096;
  unsigned short* w4l = w4h + 2048;

  hipLaunchKernelGGL(sake_prep, dim3(65), dim3(256), 0, stream,
                     h, We1, be1, We2, Wc1, Wc2, G, Base,
                     w2h, w2l, w3h, w3l, w4h, w4l);
  hipLaunchKernelGGL(sake_mfma, dim3(BB * NN), dim3(256), 0, stream,
                     h, x, mask, We1, be2, bc1, bc2,
                     Wp1, bp1, Wp2, bp2, Wn1, bn1, Wn2, bn2,
                     G, Base, w2h, w2l, w3h, w3l, w4h, w4l, out);
}